// Round 4
// baseline (541.307 us; speedup 1.0000x reference)
//
#include <hip/hip_runtime.h>
#include <stdint.h>

// Transformer block, bf16 MFMA implementation.
// B=8 T=1024 D=1024 H=16 E=64 F=4096.
#define B_ 8
#define T_ 1024
#define H_ 16
#define E_ 64
#define D_ 1024
#define F_ 4096

typedef unsigned short u16;
typedef __bf16 bf16x8 __attribute__((ext_vector_type(8)));
typedef float f32x4 __attribute__((ext_vector_type(4)));
typedef unsigned short u16x4 __attribute__((ext_vector_type(4)));

__device__ __forceinline__ u16 f2bf(float f) {
    unsigned int u = __builtin_bit_cast(unsigned int, f);
    u = (u + 0x7FFFu + ((u >> 16) & 1u)) >> 16;   // RNE
    return (u16)u;
}
__device__ __forceinline__ float bf2f(u16 h) {
    unsigned int u = ((unsigned int)h) << 16;
    return __builtin_bit_cast(float, u);
}

// async global->LDS DMA, 16B/lane; LDS dest = wave-uniform base + lane*16
__device__ __forceinline__ void async_b128(const u16* g, u16* l) {
    __builtin_amdgcn_global_load_lds(
        (const __attribute__((address_space(1))) void*)g,
        (__attribute__((address_space(3))) void*)l,
        16, 0, 0);
}

// ---------------- LayerNorm (fp32 in -> bf16 out) ----------------
__global__ __launch_bounds__(256) void ln_f32_kernel(const float* __restrict__ x,
        const float* __restrict__ g, const float* __restrict__ be, u16* __restrict__ out)
{
    int row = blockIdx.x, t = threadIdx.x;
    const float* xr = x + (size_t)row * D_;
    float4 v = ((const float4*)xr)[t];
    float s1 = v.x + v.y + v.z + v.w;
    float s2 = v.x*v.x + v.y*v.y + v.z*v.z + v.w*v.w;
    #pragma unroll
    for (int o = 32; o >= 1; o >>= 1) { s1 += __shfl_xor(s1, o); s2 += __shfl_xor(s2, o); }
    __shared__ float red[8];
    if ((t & 63) == 0) { red[(t>>6)*2] = s1; red[(t>>6)*2+1] = s2; }
    __syncthreads();
    s1 = red[0]+red[2]+red[4]+red[6];
    s2 = red[1]+red[3]+red[5]+red[7];
    float mu = s1 * (1.0f/D_);
    float rs = rsqrtf(s2*(1.0f/D_) - mu*mu + 1e-5f);
    float4 gv = ((const float4*)g)[t];
    float4 bv = ((const float4*)be)[t];
    u16 o0 = f2bf((v.x-mu)*rs*gv.x + bv.x);
    u16 o1 = f2bf((v.y-mu)*rs*gv.y + bv.y);
    u16 o2 = f2bf((v.z-mu)*rs*gv.z + bv.z);
    u16 o3 = f2bf((v.w-mu)*rs*gv.w + bv.w);
    uint2 pk; pk.x = (unsigned)o0 | ((unsigned)o1<<16); pk.y = (unsigned)o2 | ((unsigned)o3<<16);
    *(uint2*)(out + (size_t)row*D_ + t*4) = pk;
}

// ---------------- LayerNorm (bf16 in -> bf16 out) ----------------
__global__ __launch_bounds__(256) void ln_bf16_kernel(const u16* __restrict__ x,
        const float* __restrict__ g, const float* __restrict__ be, u16* __restrict__ out)
{
    int row = blockIdx.x, t = threadIdx.x;
    const u16* xr = x + (size_t)row * D_;
    u16x4 u = *(const u16x4*)(xr + t*4);
    float vx = bf2f(u.x), vy = bf2f(u.y), vz = bf2f(u.z), vw = bf2f(u.w);
    float s1 = vx + vy + vz + vw;
    float s2 = vx*vx + vy*vy + vz*vz + vw*vw;
    #pragma unroll
    for (int o = 32; o >= 1; o >>= 1) { s1 += __shfl_xor(s1, o); s2 += __shfl_xor(s2, o); }
    __shared__ float red[8];
    if ((t & 63) == 0) { red[(t>>6)*2] = s1; red[(t>>6)*2+1] = s2; }
    __syncthreads();
    s1 = red[0]+red[2]+red[4]+red[6];
    s2 = red[1]+red[3]+red[5]+red[7];
    float mu = s1 * (1.0f/D_);
    float rs = rsqrtf(s2*(1.0f/D_) - mu*mu + 1e-5f);
    float4 gv = ((const float4*)g)[t];
    float4 bv = ((const float4*)be)[t];
    u16 o0 = f2bf((vx-mu)*rs*gv.x + bv.x);
    u16 o1 = f2bf((vy-mu)*rs*gv.y + bv.y);
    u16 o2 = f2bf((vz-mu)*rs*gv.z + bv.z);
    u16 o3 = f2bf((vw-mu)*rs*gv.w + bv.w);
    uint2 pk; pk.x = (unsigned)o0 | ((unsigned)o1<<16); pk.y = (unsigned)o2 | ((unsigned)o3<<16);
    *(uint2*)(out + (size_t)row*D_ + t*4) = pk;
}

// ---------- transpose+convert fp32 [R,C] -> bf16 [C,R] (64x64 tiles) ----------
__global__ __launch_bounds__(256) void tcvt_kernel(const float* __restrict__ src,
        u16* __restrict__ dst, int R, int C, long sbatch, long dbatch)
{
    __shared__ float tile[64*65];
    int t = threadIdx.x;
    int c0 = blockIdx.x * 64, r0 = blockIdx.y * 64;
    const float* s = src + (long)blockIdx.z * sbatch;
    u16* d = dst + (long)blockIdx.z * dbatch;
    #pragma unroll
    for (int i = 0; i < 16; i++) {
        int e = t + i*256, rr = e >> 6, cc = e & 63;
        tile[rr*65 + cc] = s[(size_t)(r0+rr)*C + c0+cc];
    }
    __syncthreads();
    #pragma unroll
    for (int i = 0; i < 16; i++) {
        int e = t + i*256, rr = e >> 6, cc = e & 63;
        d[(size_t)(c0+rr)*R + r0+cc] = f2bf(tile[cc*65 + rr]);
    }
}

// ---------- QKV weights [H,1024,64] x3 -> bf16 [3072,1024] in ONE launch ----------
__global__ __launch_bounds__(256) void tcvt_qkv_kernel(const float* __restrict__ wq,
        const float* __restrict__ wk, const float* __restrict__ wv, u16* __restrict__ dst)
{
    __shared__ float tile[64*65];
    int t = threadIdx.x;
    int z = blockIdx.z;                 // 0..47
    int iw = z >> 4, h = z & 15;
    const float* s = (iw == 0 ? wq : (iw == 1 ? wk : wv)) + (long)h * 65536;
    u16* d = dst + (long)iw * (1024*1024) + (long)h * 64 * 1024;
    int r0 = blockIdx.y * 64;           // blockIdx.y in 0..15 (rows of the 1024)
    #pragma unroll
    for (int i = 0; i < 16; i++) {
        int e = t + i*256, rr = e >> 6, cc = e & 63;
        tile[rr*65 + cc] = s[(size_t)(r0+rr)*64 + cc];
    }
    __syncthreads();
    #pragma unroll
    for (int i = 0; i < 16; i++) {
        int e = t + i*256, rr = e >> 6, cc = e & 63;
        d[(size_t)rr*1024 + r0+cc] = f2bf(tile[cc*65 + rr]);
    }
}

// ---------- transpose V slice of qkv [B*T,3072] -> vT [B*H*E, T] (bf16) ----------
__global__ __launch_bounds__(256) void vtrans_kernel(const u16* __restrict__ qkv,
        u16* __restrict__ vT)
{
    __shared__ u16 tl[64*65];
    int t = threadIdx.x;
    int bh = blockIdx.y, b = bh >> 4, h = bh & 15;
    int t0 = blockIdx.x * 64;
    #pragma unroll
    for (int i = 0; i < 16; i++) {
        int e = t + i*256, rr = e >> 6, cc = e & 63;
        tl[rr*65 + cc] = qkv[(size_t)(b*T_ + t0 + rr)*3072 + 2048 + h*E_ + cc];
    }
    __syncthreads();
    #pragma unroll
    for (int i = 0; i < 16; i++) {
        int e = t + i*256, rr = e >> 6, cc = e & 63;
        vT[(size_t)(bh*E_ + rr)*T_ + t0 + cc] = tl[cc*65 + rr];
    }
}

// ---------------- bf16 MFMA GEMM:  C = A * Bt^T, 128x128 ----------------
// 256 thr, 4 waves 2x2, 64x64/wave.
// R4: row-stripe XCD mapping (R3-proven: FETCH 282->75MB) + QUAD-buffered
// depth-3 DMA prefetch, retested in the NEW regime (R1's depth-3 null was
// measured under a saturated L2-fill path -> uninterpretable; now BW has
// headroom and the residual per-iter stall matches exposed DMA latency).
// Loop: wait vmcnt(8) [slab k landed; k+1,k+2 in flight] -> barrier ->
// issue slab k+3 -> compute slab k. Cover ~3 compute phases (~1800cy).
// LDS 4x16KB = 64KB -> still 2 blocks/CU. flags: 1=relu, 2=fp32 out.
__global__ __launch_bounds__(256) void gemm128(
        const u16* __restrict__ A, const u16* __restrict__ Bt,
        int M, int N, int K,
        const float* __restrict__ bias, const u16* __restrict__ res,
        void* __restrict__ out, int flags)
{
    __shared__ __align__(16) u16 lA[4][128*32];
    __shared__ __align__(16) u16 lB[4][128*32];
    int t = threadIdx.x;
    int l = t & 63, l16 = l & 15, quad = l >> 4;
    int w = t >> 6, wm = w >> 1, wn = w & 1;

    // row-stripe XCD mapping (grid must be (8,64)): xcd == blockIdx.x owns
    // an 8-row bm stripe x ALL bn -> k-slabs shared by co-resident blocks.
    int bm = blockIdx.x * 8 + (blockIdx.y & 7);
    int bn = blockIdx.y >> 3;
    long mBase = (long)bm * 128;
    long nBase = (long)bn * 128;

    f32x4 zz = {0.f, 0.f, 0.f, 0.f};
    f32x4 acc[4][4];
    #pragma unroll
    for (int mt = 0; mt < 4; mt++)
        #pragma unroll
        for (int nt = 0; nt < 4; nt++) acc[mt][nt] = zz;

    int srow = l >> 2;
    int chunk = (l & 3) ^ ((l >> 3) & 3);
    const u16* gA0 = A  + (size_t)(mBase + w*32 +      srow) * K + chunk*8;
    const u16* gA1 = A  + (size_t)(mBase + w*32 + 16 + srow) * K + chunk*8;
    const u16* gB0 = Bt + (size_t)(nBase + w*32 +      srow) * K + chunk*8;
    const u16* gB1 = Bt + (size_t)(nBase + w*32 + 16 + srow) * K + chunk*8;
    int ldsOff0 = (w*32     )*32;
    int ldsOff1 = (w*32 + 16)*32;

    int fchunk = (quad ^ ((l16 >> 1) & 3)) * 8;
    int nIter = K >> 5;

    // prologue: issue slabs 0,1,2 (nIter >= 32 for all call sites)
    #pragma unroll
    for (int s = 0; s < 3; s++) {
        int koff = s * 32;
        async_b128(gA0 + koff, &lA[s][ldsOff0]);
        async_b128(gA1 + koff, &lA[s][ldsOff1]);
        async_b128(gB0 + koff, &lB[s][ldsOff0]);
        async_b128(gB1 + koff, &lB[s][ldsOff1]);
    }

    int cur = 0, nxt = 3;
    for (int k = 0; k < nIter; k++) {
        // slab k's 4 loads complete; slabs k+1,k+2 (8 loads) stay in flight
        asm volatile("s_waitcnt vmcnt(8)" ::: "memory");
        asm volatile("s_barrier" ::: "memory");
        // issue slab k+3 into the buffer freed by compute(k-1)
        int k3 = k + 3;
        int koff = (k3 < nIter) ? k3 * 32 : 0;   // dummy reloads keep vmcnt ladder valid
        async_b128(gA0 + koff, &lA[nxt][ldsOff0]);
        async_b128(gA1 + koff, &lA[nxt][ldsOff1]);
        async_b128(gB0 + koff, &lB[nxt][ldsOff0]);
        async_b128(gB1 + koff, &lB[nxt][ldsOff1]);
        bf16x8 af[4], bfr[4];
        #pragma unroll
        for (int mt = 0; mt < 4; mt++)
            af[mt] = *(const bf16x8*)&lA[cur][(wm*64 + mt*16 + l16)*32 + fchunk];
        #pragma unroll
        for (int nt = 0; nt < 4; nt++)
            bfr[nt] = *(const bf16x8*)&lB[cur][(wn*64 + nt*16 + l16)*32 + fchunk];
        #pragma unroll
        for (int mt = 0; mt < 4; mt++)
            #pragma unroll
            for (int nt = 0; nt < 4; nt++)
                acc[mt][nt] = __builtin_amdgcn_mfma_f32_16x16x32_bf16(af[mt], bfr[nt], acc[mt][nt], 0, 0, 0);
        cur = (cur + 1) & 3;
        nxt = (nxt + 1) & 3;
    }

    int do_relu = flags & 1, f32o = flags & 2;
    #pragma unroll
    for (int mt = 0; mt < 4; mt++) {
        #pragma unroll
        for (int nt = 0; nt < 4; nt++) {
            long gn = nBase + wn*64 + nt*16 + l16;
            float bv = bias ? bias[gn] : 0.0f;
            #pragma unroll
            for (int r = 0; r < 4; r++) {
                long gm = mBase + wm*64 + mt*16 + quad*4 + r;
                float v = acc[mt][nt][r] + bv;
                if (res) v += bf2f(res[(size_t)gm*N + gn]);
                if (do_relu) v = fmaxf(v, 0.0f);
                if (f32o) ((float*)out)[(size_t)gm*N + gn] = v;
                else      ((u16*)out)[(size_t)gm*N + gn] = f2bf(v);
            }
        }
    }
}

// ---------------- FAT bf16 MFMA GEMM:  256x256 block, 512 thr ----------------
// 8 waves arranged 2(wm) x 4(wn); wave tile 128x64 (8 mt x 4 nt of 16x16x32).
// Triple-buffered slabs (3 x 32KB = 96KB, 1 block/CU, 2 waves/SIMD),
// depth-1 DMA prefetch, vmcnt(4), one raw barrier/iter (R0/R3-proven; kept
// UNCHANGED this round for a clean single-variable A/B on gemm128).
__global__ __launch_bounds__(512, 2) void gemm_fat(
        const u16* __restrict__ A, const u16* __restrict__ Bt,
        int M, int N, int K,
        const float* __restrict__ bias, const u16* __restrict__ res,
        void* __restrict__ out, int flags)
{
    __shared__ __align__(16) u16 lA[3][256*32];
    __shared__ __align__(16) u16 lB[3][256*32];
    int t = threadIdx.x;
    int l = t & 63, l16 = l & 15, quad = l >> 4;
    int w = t >> 6;                 // 0..7
    int wm = w >> 2, wn = w & 3;    // 2 x 4
    long mBase = (long)blockIdx.y * 256;
    long nBase = (long)blockIdx.x * 256;

    f32x4 zz = {0.f, 0.f, 0.f, 0.f};
    f32x4 acc[8][4];
    #pragma unroll
    for (int mt = 0; mt < 8; mt++)
        #pragma unroll
        for (int nt = 0; nt < 4; nt++) acc[mt][nt] = zz;

    // staging: wave w covers rows w*32..w*32+31 of both A and B tiles (256 rows)
    int srow = l >> 2;
    int chunk = (l & 3) ^ ((l >> 3) & 3);
    const u16* gA0 = A  + (size_t)(mBase + w*32 +      srow) * K + chunk*8;
    const u16* gA1 = A  + (size_t)(mBase + w*32 + 16 + srow) * K + chunk*8;
    const u16* gB0 = Bt + (size_t)(nBase + w*32 +      srow) * K + chunk*8;
    const u16* gB1 = Bt + (size_t)(nBase + w*32 + 16 + srow) * K + chunk*8;
    int ldsOff0 = (w*32     )*32;
    int ldsOff1 = (w*32 + 16)*32;

    int fchunk = (quad ^ ((l16 >> 1) & 3)) * 8;
    int nIter = K >> 5;

    async_b128(gA0, &lA[0][ldsOff0]);
    async_b128(gA1, &lA[0][ldsOff1]);
    async_b128(gB0, &lB[0][ldsOff0]);
    async_b128(gB1, &lB[0][ldsOff1]);

    int cur = 0, nxt = 1;
    for (int k = 0; k < nIter; k++) {
        int koff = (k + 1 < nIter) ? (k + 1) * 32 : 0;
        async_b128(gA0 + koff, &lA[nxt][ldsOff0]);
        async_b128(gA1 + koff, &lA[nxt][ldsOff1]);
        async_b128(gB0 + koff, &lB[nxt][ldsOff0]);
        async_b128(gB1 + koff, &lB[nxt][ldsOff1]);
        asm volatile("s_waitcnt vmcnt(4)" ::: "memory");
        asm volatile("s_barrier" ::: "memory");
        bf16x8 bfr[4];
        #pragma unroll
        for (int nt = 0; nt < 4; nt++)
            bfr[nt] = *(const bf16x8*)&lB[cur][(wn*64 + nt*16 + l16)*32 + fchunk];
        #pragma unroll
        for (int mt = 0; mt < 8; mt++) {
            bf16x8 af = *(const bf16x8*)&lA[cur][(wm*128 + mt*16 + l16)*32 + fchunk];
            #pragma unroll
            for (int nt = 0; nt < 4; nt++)
                acc[mt][nt] = __builtin_amdgcn_mfma_f32_16x16x32_bf16(af, bfr[nt], acc[mt][nt], 0, 0, 0);
        }
        cur = nxt;
        nxt = nxt + 1; if (nxt == 3) nxt = 0;
    }

    int do_relu = flags & 1;
    #pragma unroll
    for (int mt = 0; mt < 8; mt++) {
        #pragma unroll
        for (int nt = 0; nt < 4; nt++) {
            long gn = nBase + wn*64 + nt*16 + l16;
            float bv = bias ? bias[gn] : 0.0f;
            #pragma unroll
            for (int r = 0; r < 4; r++) {
                long gm = mBase + wm*128 + mt*16 + quad*4 + r;
                float v = acc[mt][nt][r] + bv;
                if (do_relu) v = fmaxf(v, 0.0f);
                ((u16*)out)[(size_t)gm*N + gn] = f2bf(v);
            }
        }
    }
}

// ---------------- fused causal flash attention (bf16 MFMA) ----------------
// R3-proven: paired tiles (grid (8,128), block does q-tile a and 15-a ->
// exactly 17 chunks/block, zero tail imbalance) + T14 async-STAGE (next
// chunk's K/V global-loaded into regs during compute).
__global__ __launch_bounds__(256) void attn_kernel(
        const u16* __restrict__ qkv, const u16* __restrict__ vT, u16* __restrict__ out)
{
    constexpr int LS = 72;
    __shared__ __align__(16) u16 q_lds[64*LS];
    __shared__ __align__(16) u16 k_lds[64*LS];
    __shared__ __align__(16) u16 v_lds[64*LS];
    __shared__ __align__(16) u16 p_lds[64*LS];
    int t = threadIdx.x;
    int w = t >> 6, l = t & 63, l16 = l & 15, quad = l >> 4;
    int bh = blockIdx.y, b = bh >> 4, h = bh & 15;
    int rr = t >> 2, c = (t & 3) * 16;   // staging coords (64 rows x 64 cols)

    for (int pass = 0; pass < 2; pass++) {
        int qt = pass ? (15 - (int)blockIdx.x) : (int)blockIdx.x;
        int t0 = qt * 64;

        __syncthreads();   // protect q_lds/k/v reuse across passes
        {
            const u16* src = qkv + (size_t)(b*T_ + t0 + rr)*3072 + h*E_ + c;
            *(bf16x8*)&q_lds[rr*LS + c]     = *(const bf16x8*)(src);
            *(bf16x8*)&q_lds[rr*LS + c + 8] = *(const bf16x8*)(src + 8);
        }
        __syncthreads();
        bf16x8 qf0 = *(const bf16x8*)&q_lds[(w*16 + l16)*LS + quad*8];
        bf16x8 qf1 = *(const bf16x8*)&q_lds[(w*16 + l16)*LS + 32 + quad*8];

        float m_[4], l_[4];
        f32x4 O[4];
        f32x4 zz = {0.f, 0.f, 0.f, 0.f};
        #pragma unroll
        for (int r = 0; r < 4; r++) { m_[r] = -1e30f; l_[r] = 0.0f; }
        #pragma unroll
        for (int d = 0; d < 4; d++) O[d] = zz;

        // prefetch K/V chunk 0 into registers
        bf16x8 kr0, kr1, vr0, vr1;
        {
            const u16* ks = qkv + (size_t)(b*T_ + 0 + rr)*3072 + 1024 + h*E_ + c;
            kr0 = *(const bf16x8*)(ks);
            kr1 = *(const bf16x8*)(ks + 8);
            const u16* vs = vT + (size_t)(bh*E_ + rr)*T_ + 0 + c;
            vr0 = *(const bf16x8*)(vs);
            vr1 = *(const bf16x8*)(vs + 8);
        }

        int nchunk = qt + 1;
        for (int ch = 0; ch < nchunk; ch++) {
            int j0 = ch * 64;
            __syncthreads();   // previous chunk's compute done -> LDS free
            // staged regs -> LDS (no global latency here)
            *(bf16x8*)&k_lds[rr*LS + c]     = kr0;
            *(bf16x8*)&k_lds[rr*LS + c + 8] = kr1;
            *(bf16x8*)&v_lds[rr*LS + c]     = vr0;
            *(bf16x8*)&v_lds[rr*LS + c + 8] = vr1;
            // issue next chunk's global loads; they complete under compute
            if (ch + 1 < nchunk) {
                int j1 = (ch + 1) * 64;
                const u16* ks = qkv + (size_t)(b*T_ + j1 + rr)*3072 + 1024 + h*E_ + c;
                kr0 = *(const bf16x8*)(ks);
                kr1 = *(const bf16x8*)(ks + 8);
                const u16* vs = vT + (size_t)(bh*E_ + rr)*T_ + j1 + c;
                vr0 = *(const bf16x8*)(vs);
                vr1 = *(const bf16x8*)(vs + 8);
            }
            __syncthreads();

            f32x4 S[4];
            #pragma unroll
            for (int nt = 0; nt < 4; nt++) {
                bf16x8 k0f = *(const bf16x8*)&k_lds[(nt*16 + l16)*LS + quad*8];
                bf16x8 k1f = *(const bf16x8*)&k_lds[(nt*16 + l16)*LS + 32 + quad*8];
                f32x4 z = zz;
                z = __builtin_amdgcn_mfma_f32_16x16x32_bf16(qf0, k0f, z, 0, 0, 0);
                z = __builtin_amdgcn_mfma_f32_16x16x32_bf16(qf1, k1f, z, 0, 0, 0);
                S[nt] = z;
            }
            int rowg = t0 + w*16 + quad*4;
            float P[4][4], mx[4];
            #pragma unroll
            for (int r = 0; r < 4; r++) mx[r] = -1e30f;
            #pragma unroll
            for (int nt = 0; nt < 4; nt++) {
                int colg = j0 + nt*16 + l16;
                #pragma unroll
                for (int r = 0; r < 4; r++) {
                    float s = S[nt][r] * 0.125f;
                    s = (colg > rowg + r) ? -1e30f : s;
                    P[nt][r] = s;
                    mx[r] = fmaxf(mx[r], s);
                }
            }
            #pragma unroll
            for (int o = 1; o < 16; o <<= 1)
                #pragma unroll
                for (int r = 0; r < 4; r++) mx[r] = fmaxf(mx[r], __shfl_xor(mx[r], o));
            float alpha[4], rsum[4];
            #pragma unroll
            for (int r = 0; r < 4; r++) {
                float mn = fmaxf(m_[r], mx[r]);
                alpha[r] = __expf(m_[r] - mn);
                m_[r] = mn;
                rsum[r] = 0.0f;
            }
            #pragma unroll
            for (int nt = 0; nt < 4; nt++)
                #pragma unroll
                for (int r = 0; r < 4; r++) {
                    float p = __expf(P[nt][r] - m_[r]);
                    P[nt][r] = p;
                    rsum[r] += p;
                }
            #pragma unroll
            for (int o = 1; o < 16; o <<= 1)
                #pragma unroll
                for (int r = 0; r < 4; r++) rsum[r] += __shfl_xor(rsum[r], o);
            #pragma unroll
            for (int r = 0; r < 4; r++) l_[r] = l_[r]*alpha[r] + rsum[r];
            #pragma unroll
            for (int d = 0; d < 4; d++)
                #pragma unroll
                for (int r = 0; r < 4; r++) O[d][r] *= alpha[r];

            #pragma unroll
            for (int nt = 0; nt < 4; nt++)
                #pragma unroll
                for (int r = 0; r < 4; r++)
                    p_lds[(w*16 + quad*4 + r)*LS + nt*16 + l16] = f2bf(P[nt][r]);
            bf16x8 pf0 = *(const bf16x8*)&p_lds[(w*16 + l16)*LS + quad*8];
            bf16x8 pf1 = *(const bf16x8*)&p_lds[(w*16 + l16)*LS + 32 + quad*8];
            #pragma unroll
            for (int d = 0; d < 4; d++) {
                bf16x8 v0f = *(const bf16x8*)&v_lds[(d*16 + l16)*LS + quad*8];
                bf16x8 v1f = *(const bf16x8*)&v_lds[(d*16 + l16)*LS + 32 + quad*8];
                O[d] = __builtin_amdgcn_mfma_f32_16x16x32_bf16(pf0, v0f, O[d], 0, 0, 0);
                O[d] = __builtin_amdgcn_mfma_f32_16x16x32_bf16(pf1, v1f, O[d], 0, 0, 0);
            }
        }

        #pragma unroll
        for (int r = 0; r < 4; r++) {
            float rl = 1.0f / l_[r];
            int tg = t0 + w*16 + quad*4 + r;
            #pragma unroll
            for (int d = 0; d < 4; d++)
                out[(size_t)(b*T_ + tg)*D_ + h*E_ + d*16 + l16] = f2bf(O[d][r] * rl);
        }
    }
}

extern "C" void kernel_launch(void* const* d_in, const int* in_sizes, int n_in,
                              void* d_out, int out_size, void* d_ws, size_t ws_size,
                              hipStream_t stream) {
    (void)in_sizes; (void)n_in; (void)out_size; (void)ws_size;
    const float* x      = (const float*)d_in[0];
    const float* wq     = (const float*)d_in[1];
    const float* wk     = (const float*)d_in[2];
    const float* wv     = (const float*)d_in[3];
    const float* w_proj = (const float*)d_in[4];
    const float* b_proj = (const float*)d_in[5];
    const float* w1     = (const float*)d_in[6];
    const float* b1     = (const float*)d_in[7];
    const float* w2     = (const float*)d_in[8];
    const float* b2     = (const float*)d_in[9];
    const float* g1     = (const float*)d_in[10];
    const float* be1    = (const float*)d_in[11];
    const float* g2     = (const float*)d_in[12];
    const float* be2    = (const float*)d_in[13];

    const size_t MB = 1024*1024;
    char* wsb = (char*)d_ws;
    u16* xn    = (u16*)(wsb + 0);          // 16MB  LN1(x) bf16
    u16* qkvb  = (u16*)(wsb + 16*MB);      // 48MB  [B*T,3072] q|k|v
    u16* h1    = (u16*)(wsb + 16*MB);      // 64MB  (reuses qkv+vT after attention)
    u16* vTb   = (u16*)(wsb + 64*MB);      // 16MB  [B*H*E, T]
    u16* attnb = (u16*)(wsb + 80*MB);      // 16MB  [B*T, D] concat heads
    u16* y1b   = (u16*)(wsb + 96*MB);      // 16MB  xn + proj out
    u16* xn2   = (u16*)(wsb + 112*MB);     // 16MB  LN2(y1)
    u16* WqkvT = (u16*)(wsb + 128*MB);     // 6MB   [3072,1024]
    u16* WprojT= (u16*)(wsb + 134*MB);     // 2MB   [1024,1024]
    u16* W1T   = (u16*)(wsb + 136*MB);     // 8MB   [4096,1024]
    u16* W2T   = (u16*)(wsb + 144*MB);     // 8MB   [1024,4096]  (ends at 152MB)

    // 1) LN1
    ln_f32_kernel<<<8192, 256, 0, stream>>>(x, g1, be1, xn);
    // 2) weights -> transposed bf16
    tcvt_qkv_kernel<<<dim3(1,16,48), 256, 0, stream>>>(wq, wk, wv, WqkvT);
    tcvt_kernel<<<dim3(16,16,1), 256, 0, stream>>>(w_proj, WprojT, 1024, 1024, 0, 0);
    tcvt_kernel<<<dim3(64,16,1), 256, 0, stream>>>(w1, W1T, 1024, 4096, 0, 0);
    tcvt_kernel<<<dim3(16,64,1), 256, 0, stream>>>(w2, W2T, 4096, 1024, 0, 0);
    // 3) QKV projection (fat 256x256)
    gemm_fat<<<dim3(12,32), 512, 0, stream>>>(xn, WqkvT, 8192, 3072, 1024,
                                              nullptr, nullptr, qkvb, 0);
    // 4) V -> [B,H,E,T]
    vtrans_kernel<<<dim3(16,128), 256, 0, stream>>>(qkvb, vTb);
    // 5) causal attention (paired tiles: 8 x 128 grid, 17 chunks/block)
    attn_kernel<<<dim3(8,128), 256, 0, stream>>>(qkvb, vTb, attnb);
    // 6) out projection + bias + residual(xn)  [residual uses NORMED x, faithful]
    gemm128<<<dim3(8,64), 256, 0, stream>>>(attnb, WprojT, 8192, 1024, 1024,
                                            b_proj, xn, y1b, 0);
    // 7) LN2
    ln_bf16_kernel<<<8192, 256, 0, stream>>>(y1b, g2, be2, xn2);
    // 8) FFN1 + bias + relu (fat 256x256)
    gemm_fat<<<dim3(16,32), 512, 0, stream>>>(xn2, W1T, 8192, 4096, 1024,
                                              b1, nullptr, h1, 1);
    // 9) FFN2 + bias + residual(xn2)  [residual uses NORMED y1, faithful] -> fp32 out
    gemm128<<<dim3(8,64), 256, 0, stream>>>(h1, W2T, 8192, 1024, 4096,
                                            b2, xn2, d_out, 2);
}

// Round 6
// 532.819 us; speedup vs baseline: 1.0159x; 1.0159x over previous
//
#include <hip/hip_runtime.h>
#include <stdint.h>

// Transformer block, bf16 MFMA implementation.
// B=8 T=1024 D=1024 H=16 E=64 F=4096.
#define B_ 8
#define T_ 1024
#define H_ 16
#define E_ 64
#define D_ 1024
#define F_ 4096

typedef unsigned short u16;
typedef __bf16 bf16x8 __attribute__((ext_vector_type(8)));
typedef float f32x4 __attribute__((ext_vector_type(4)));
typedef unsigned short u16x4 __attribute__((ext_vector_type(4)));

__device__ __forceinline__ u16 f2bf(float f) {
    unsigned int u = __builtin_bit_cast(unsigned int, f);
    u = (u + 0x7FFFu + ((u >> 16) & 1u)) >> 16;   // RNE
    return (u16)u;
}
__device__ __forceinline__ float bf2f(u16 h) {
    unsigned int u = ((unsigned int)h) << 16;
    return __builtin_bit_cast(float, u);
}

// async global->LDS DMA, 16B/lane; LDS dest = wave-uniform base + lane*16
__device__ __forceinline__ void async_b128(const u16* g, u16* l) {
    __builtin_amdgcn_global_load_lds(
        (const __attribute__((address_space(1))) void*)g,
        (__attribute__((address_space(3))) void*)l,
        16, 0, 0);
}

// ---------------- LayerNorm (fp32 in -> bf16 out) ----------------
__global__ __launch_bounds__(256) void ln_f32_kernel(const float* __restrict__ x,
        const float* __restrict__ g, const float* __restrict__ be, u16* __restrict__ out)
{
    int row = blockIdx.x, t = threadIdx.x;
    const float* xr = x + (size_t)row * D_;
    float4 v = ((const float4*)xr)[t];
    float s1 = v.x + v.y + v.z + v.w;
    float s2 = v.x*v.x + v.y*v.y + v.z*v.z + v.w*v.w;
    #pragma unroll
    for (int o = 32; o >= 1; o >>= 1) { s1 += __shfl_xor(s1, o); s2 += __shfl_xor(s2, o); }
    __shared__ float red[8];
    if ((t & 63) == 0) { red[(t>>6)*2] = s1; red[(t>>6)*2+1] = s2; }
    __syncthreads();
    s1 = red[0]+red[2]+red[4]+red[6];
    s2 = red[1]+red[3]+red[5]+red[7];
    float mu = s1 * (1.0f/D_);
    float rs = rsqrtf(s2*(1.0f/D_) - mu*mu + 1e-5f);
    float4 gv = ((const float4*)g)[t];
    float4 bv = ((const float4*)be)[t];
    u16 o0 = f2bf((v.x-mu)*rs*gv.x + bv.x);
    u16 o1 = f2bf((v.y-mu)*rs*gv.y + bv.y);
    u16 o2 = f2bf((v.z-mu)*rs*gv.z + bv.z);
    u16 o3 = f2bf((v.w-mu)*rs*gv.w + bv.w);
    uint2 pk; pk.x = (unsigned)o0 | ((unsigned)o1<<16); pk.y = (unsigned)o2 | ((unsigned)o3<<16);
    *(uint2*)(out + (size_t)row*D_ + t*4) = pk;
}

// ---------------- LayerNorm (bf16 in -> bf16 out) ----------------
__global__ __launch_bounds__(256) void ln_bf16_kernel(const u16* __restrict__ x,
        const float* __restrict__ g, const float* __restrict__ be, u16* __restrict__ out)
{
    int row = blockIdx.x, t = threadIdx.x;
    const u16* xr = x + (size_t)row * D_;
    u16x4 u = *(const u16x4*)(xr + t*4);
    float vx = bf2f(u.x), vy = bf2f(u.y), vz = bf2f(u.z), vw = bf2f(u.w);
    float s1 = vx + vy + vz + vw;
    float s2 = vx*vx + vy*vy + vz*vz + vw*vw;
    #pragma unroll
    for (int o = 32; o >= 1; o >>= 1) { s1 += __shfl_xor(s1, o); s2 += __shfl_xor(s2, o); }
    __shared__ float red[8];
    if ((t & 63) == 0) { red[(t>>6)*2] = s1; red[(t>>6)*2+1] = s2; }
    __syncthreads();
    s1 = red[0]+red[2]+red[4]+red[6];
    s2 = red[1]+red[3]+red[5]+red[7];
    float mu = s1 * (1.0f/D_);
    float rs = rsqrtf(s2*(1.0f/D_) - mu*mu + 1e-5f);
    float4 gv = ((const float4*)g)[t];
    float4 bv = ((const float4*)be)[t];
    u16 o0 = f2bf((vx-mu)*rs*gv.x + bv.x);
    u16 o1 = f2bf((vy-mu)*rs*gv.y + bv.y);
    u16 o2 = f2bf((vz-mu)*rs*gv.z + bv.z);
    u16 o3 = f2bf((vw-mu)*rs*gv.w + bv.w);
    uint2 pk; pk.x = (unsigned)o0 | ((unsigned)o1<<16); pk.y = (unsigned)o2 | ((unsigned)o3<<16);
    *(uint2*)(out + (size_t)row*D_ + t*4) = pk;
}

// ---------- transpose+convert fp32 [R,C] -> bf16 [C,R] (64x64 tiles) ----------
__global__ __launch_bounds__(256) void tcvt_kernel(const float* __restrict__ src,
        u16* __restrict__ dst, int R, int C, long sbatch, long dbatch)
{
    __shared__ float tile[64*65];
    int t = threadIdx.x;
    int c0 = blockIdx.x * 64, r0 = blockIdx.y * 64;
    const float* s = src + (long)blockIdx.z * sbatch;
    u16* d = dst + (long)blockIdx.z * dbatch;
    #pragma unroll
    for (int i = 0; i < 16; i++) {
        int e = t + i*256, rr = e >> 6, cc = e & 63;
        tile[rr*65 + cc] = s[(size_t)(r0+rr)*C + c0+cc];
    }
    __syncthreads();
    #pragma unroll
    for (int i = 0; i < 16; i++) {
        int e = t + i*256, rr = e >> 6, cc = e & 63;
        d[(size_t)(c0+rr)*R + r0+cc] = f2bf(tile[cc*65 + rr]);
    }
}

// ---------- QKV weights [H,1024,64] x3 -> bf16 [3072,1024] in ONE launch ----------
__global__ __launch_bounds__(256) void tcvt_qkv_kernel(const float* __restrict__ wq,
        const float* __restrict__ wk, const float* __restrict__ wv, u16* __restrict__ dst)
{
    __shared__ float tile[64*65];
    int t = threadIdx.x;
    int z = blockIdx.z;                 // 0..47
    int iw = z >> 4, h = z & 15;
    const float* s = (iw == 0 ? wq : (iw == 1 ? wk : wv)) + (long)h * 65536;
    u16* d = dst + (long)iw * (1024*1024) + (long)h * 64 * 1024;
    int r0 = blockIdx.y * 64;           // blockIdx.y in 0..15 (rows of the 1024)
    #pragma unroll
    for (int i = 0; i < 16; i++) {
        int e = t + i*256, rr = e >> 6, cc = e & 63;
        tile[rr*65 + cc] = s[(size_t)(r0+rr)*64 + cc];
    }
    __syncthreads();
    #pragma unroll
    for (int i = 0; i < 16; i++) {
        int e = t + i*256, rr = e >> 6, cc = e & 63;
        d[(size_t)rr*1024 + r0+cc] = f2bf(tile[cc*65 + rr]);
    }
}

// ---------- transpose V slice of qkv [B*T,3072] -> vT [B*H*E, T] (bf16) ----------
__global__ __launch_bounds__(256) void vtrans_kernel(const u16* __restrict__ qkv,
        u16* __restrict__ vT)
{
    __shared__ u16 tl[64*65];
    int t = threadIdx.x;
    int bh = blockIdx.y, b = bh >> 4, h = bh & 15;
    int t0 = blockIdx.x * 64;
    #pragma unroll
    for (int i = 0; i < 16; i++) {
        int e = t + i*256, rr = e >> 6, cc = e & 63;
        tl[rr*65 + cc] = qkv[(size_t)(b*T_ + t0 + rr)*3072 + 2048 + h*E_ + cc];
    }
    __syncthreads();
    #pragma unroll
    for (int i = 0; i < 16; i++) {
        int e = t + i*256, rr = e >> 6, cc = e & 63;
        vT[(size_t)(bh*E_ + rr)*T_ + t0 + cc] = tl[cc*65 + rr];
    }
}

// ---------------- bf16 MFMA GEMM:  C = A * Bt^T, 64x128 tile ----------------
// R5 (resubmit; R5 bench was an infra failure, kernel never measured):
// SAME proven pipeline as R3 (triple-buffer, depth-1, vmcnt wait, one raw
// barrier/iter — depth-3 regressed in clean A/B, R4) but tile shrunk
// 128x128 -> 64x128 to DOUBLE the grid: (8,128) = 1024 blocks = 4/CU =
// 16 waves/CU. R3/R4 counters showed the grid (512 blocks = 2/CU = 8
// waves/CU) was the binding constraint: MfmaUtil 23.7 = 37*(2/3) tracks
// resident blocks vs the m97-reference's 3/CU. LDS 3x12KB=36KB -> 4/CU ok.
// 4 waves 2x2, wave tile 32x64, acc[2][4]. Staging: wave w stages A rows
// [w*16,w*16+16) (1 DMA) + B rows [w*32,w*32+32) (2 DMAs); vmcnt(3).
// Row-stripe XCD map: xcd==blockIdx.x owns 16 m-tiles x ALL bn (R3-proven
// FETCH 282->75MB). flags: 1=relu, 2=fp32 out.
__global__ __launch_bounds__(256) void gemm128(
        const u16* __restrict__ A, const u16* __restrict__ Bt,
        int M, int N, int K,
        const float* __restrict__ bias, const u16* __restrict__ res,
        void* __restrict__ out, int flags)
{
    __shared__ __align__(16) u16 lA[3][64*32];
    __shared__ __align__(16) u16 lB[3][128*32];
    int t = threadIdx.x;
    int l = t & 63, l16 = l & 15, quad = l >> 4;
    int w = t >> 6, wm = w >> 1, wn = w & 1;

    // row-stripe XCD mapping (grid must be (8,128))
    int bm = blockIdx.x * 16 + (blockIdx.y & 15);
    int bn = blockIdx.y >> 4;
    long mBase = (long)bm * 64;
    long nBase = (long)bn * 128;

    f32x4 zz = {0.f, 0.f, 0.f, 0.f};
    f32x4 acc[2][4];
    #pragma unroll
    for (int mt = 0; mt < 2; mt++)
        #pragma unroll
        for (int nt = 0; nt < 4; nt++) acc[mt][nt] = zz;

    int srow = l >> 2;
    int chunk = (l & 3) ^ ((l >> 3) & 3);
    const u16* gA0 = A  + (size_t)(mBase + w*16 +      srow) * K + chunk*8;
    const u16* gB0 = Bt + (size_t)(nBase + w*32 +      srow) * K + chunk*8;
    const u16* gB1 = Bt + (size_t)(nBase + w*32 + 16 + srow) * K + chunk*8;
    int ldsOffA  = (w*16     )*32;
    int ldsOffB0 = (w*32     )*32;
    int ldsOffB1 = (w*32 + 16)*32;

    int fchunk = (quad ^ ((l16 >> 1) & 3)) * 8;
    int nIter = K >> 5;

    async_b128(gA0, &lA[0][ldsOffA]);
    async_b128(gB0, &lB[0][ldsOffB0]);
    async_b128(gB1, &lB[0][ldsOffB1]);

    int cur = 0, nxt = 1;
    for (int k = 0; k < nIter; k++) {
        int koff = (k + 1 < nIter) ? (k + 1) * 32 : 0;
        async_b128(gA0 + koff, &lA[nxt][ldsOffA]);
        async_b128(gB0 + koff, &lB[nxt][ldsOffB0]);
        async_b128(gB1 + koff, &lB[nxt][ldsOffB1]);
        asm volatile("s_waitcnt vmcnt(3)" ::: "memory");
        asm volatile("s_barrier" ::: "memory");
        bf16x8 af[2], bfr[4];
        #pragma unroll
        for (int mt = 0; mt < 2; mt++)
            af[mt] = *(const bf16x8*)&lA[cur][(wm*32 + mt*16 + l16)*32 + fchunk];
        #pragma unroll
        for (int nt = 0; nt < 4; nt++)
            bfr[nt] = *(const bf16x8*)&lB[cur][(wn*64 + nt*16 + l16)*32 + fchunk];
        #pragma unroll
        for (int mt = 0; mt < 2; mt++)
            #pragma unroll
            for (int nt = 0; nt < 4; nt++)
                acc[mt][nt] = __builtin_amdgcn_mfma_f32_16x16x32_bf16(af[mt], bfr[nt], acc[mt][nt], 0, 0, 0);
        cur = nxt;
        nxt = nxt + 1; if (nxt == 3) nxt = 0;
    }

    int do_relu = flags & 1, f32o = flags & 2;
    #pragma unroll
    for (int mt = 0; mt < 2; mt++) {
        #pragma unroll
        for (int nt = 0; nt < 4; nt++) {
            long gn = nBase + wn*64 + nt*16 + l16;
            float bv = bias ? bias[gn] : 0.0f;
            #pragma unroll
            for (int r = 0; r < 4; r++) {
                long gm = mBase + wm*32 + mt*16 + quad*4 + r;
                float v = acc[mt][nt][r] + bv;
                if (res) v += bf2f(res[(size_t)gm*N + gn]);
                if (do_relu) v = fmaxf(v, 0.0f);
                if (f32o) ((float*)out)[(size_t)gm*N + gn] = v;
                else      ((u16*)out)[(size_t)gm*N + gn] = f2bf(v);
            }
        }
    }
}

// ---------------- FAT bf16 MFMA GEMM:  256x256 block, 512 thr ----------------
// 8 waves arranged 2(wm) x 4(wn); wave tile 128x64 (8 mt x 4 nt of 16x16x32).
// Triple-buffered slabs (3 x 32KB = 96KB, 1 block/CU, 2 waves/SIMD),
// depth-1 DMA prefetch, vmcnt(4), one raw barrier/iter (proven; UNCHANGED).
__global__ __launch_bounds__(512, 2) void gemm_fat(
        const u16* __restrict__ A, const u16* __restrict__ Bt,
        int M, int N, int K,
        const float* __restrict__ bias, const u16* __restrict__ res,
        void* __restrict__ out, int flags)
{
    __shared__ __align__(16) u16 lA[3][256*32];
    __shared__ __align__(16) u16 lB[3][256*32];
    int t = threadIdx.x;
    int l = t & 63, l16 = l & 15, quad = l >> 4;
    int w = t >> 6;                 // 0..7
    int wm = w >> 2, wn = w & 3;    // 2 x 4
    long mBase = (long)blockIdx.y * 256;
    long nBase = (long)blockIdx.x * 256;

    f32x4 zz = {0.f, 0.f, 0.f, 0.f};
    f32x4 acc[8][4];
    #pragma unroll
    for (int mt = 0; mt < 8; mt++)
        #pragma unroll
        for (int nt = 0; nt < 4; nt++) acc[mt][nt] = zz;

    // staging: wave w covers rows w*32..w*32+31 of both A and B tiles (256 rows)
    int srow = l >> 2;
    int chunk = (l & 3) ^ ((l >> 3) & 3);
    const u16* gA0 = A  + (size_t)(mBase + w*32 +      srow) * K + chunk*8;
    const u16* gA1 = A  + (size_t)(mBase + w*32 + 16 + srow) * K + chunk*8;
    const u16* gB0 = Bt + (size_t)(nBase + w*32 +      srow) * K + chunk*8;
    const u16* gB1 = Bt + (size_t)(nBase + w*32 + 16 + srow) * K + chunk*8;
    int ldsOff0 = (w*32     )*32;
    int ldsOff1 = (w*32 + 16)*32;

    int fchunk = (quad ^ ((l16 >> 1) & 3)) * 8;
    int nIter = K >> 5;

    async_b128(gA0, &lA[0][ldsOff0]);
    async_b128(gA1, &lA[0][ldsOff1]);
    async_b128(gB0, &lB[0][ldsOff0]);
    async_b128(gB1, &lB[0][ldsOff1]);

    int cur = 0, nxt = 1;
    for (int k = 0; k < nIter; k++) {
        int koff = (k + 1 < nIter) ? (k + 1) * 32 : 0;
        async_b128(gA0 + koff, &lA[nxt][ldsOff0]);
        async_b128(gA1 + koff, &lA[nxt][ldsOff1]);
        async_b128(gB0 + koff, &lB[nxt][ldsOff0]);
        async_b128(gB1 + koff, &lB[nxt][ldsOff1]);
        asm volatile("s_waitcnt vmcnt(4)" ::: "memory");
        asm volatile("s_barrier" ::: "memory");
        bf16x8 bfr[4];
        #pragma unroll
        for (int nt = 0; nt < 4; nt++)
            bfr[nt] = *(const bf16x8*)&lB[cur][(wn*64 + nt*16 + l16)*32 + fchunk];
        #pragma unroll
        for (int mt = 0; mt < 8; mt++) {
            bf16x8 af = *(const bf16x8*)&lA[cur][(wm*128 + mt*16 + l16)*32 + fchunk];
            #pragma unroll
            for (int nt = 0; nt < 4; nt++)
                acc[mt][nt] = __builtin_amdgcn_mfma_f32_16x16x32_bf16(af, bfr[nt], acc[mt][nt], 0, 0, 0);
        }
        cur = nxt;
        nxt = nxt + 1; if (nxt == 3) nxt = 0;
    }

    int do_relu = flags & 1;
    #pragma unroll
    for (int mt = 0; mt < 8; mt++) {
        #pragma unroll
        for (int nt = 0; nt < 4; nt++) {
            long gn = nBase + wn*64 + nt*16 + l16;
            float bv = bias ? bias[gn] : 0.0f;
            #pragma unroll
            for (int r = 0; r < 4; r++) {
                long gm = mBase + wm*128 + mt*16 + quad*4 + r;
                float v = acc[mt][nt][r] + bv;
                if (do_relu) v = fmaxf(v, 0.0f);
                ((u16*)out)[(size_t)gm*N + gn] = f2bf(v);
            }
        }
    }
}

// ---------------- fused causal flash attention (bf16 MFMA) ----------------
// R3-proven: paired tiles (grid (8,128), block does q-tile a and 15-a ->
// exactly 17 chunks/block, zero tail imbalance) + T14 async-STAGE (next
// chunk's K/V global-loaded into regs during compute). UNCHANGED.
__global__ __launch_bounds__(256) void attn_kernel(
        const u16* __restrict__ qkv, const u16* __restrict__ vT, u16* __restrict__ out)
{
    constexpr int LS = 72;
    __shared__ __align__(16) u16 q_lds[64*LS];
    __shared__ __align__(16) u16 k_lds[64*LS];
    __shared__ __align__(16) u16 v_lds[64*LS];
    __shared__ __align__(16) u16 p_lds[64*LS];
    int t = threadIdx.x;
    int w = t >> 6, l = t & 63, l16 = l & 15, quad = l >> 4;
    int bh = blockIdx.y, b = bh >> 4, h = bh & 15;
    int rr = t >> 2, c = (t & 3) * 16;   // staging coords (64 rows x 64 cols)

    for (int pass = 0; pass < 2; pass++) {
        int qt = pass ? (15 - (int)blockIdx.x) : (int)blockIdx.x;
        int t0 = qt * 64;

        __syncthreads();   // protect q_lds/k/v reuse across passes
        {
            const u16* src = qkv + (size_t)(b*T_ + t0 + rr)*3072 + h*E_ + c;
            *(bf16x8*)&q_lds[rr*LS + c]     = *(const bf16x8*)(src);
            *(bf16x8*)&q_lds[rr*LS + c + 8] = *(const bf16x8*)(src + 8);
        }
        __syncthreads();
        bf16x8 qf0 = *(const bf16x8*)&q_lds[(w*16 + l16)*LS + quad*8];
        bf16x8 qf1 = *(const bf16x8*)&q_lds[(w*16 + l16)*LS + 32 + quad*8];

        float m_[4], l_[4];
        f32x4 O[4];
        f32x4 zz = {0.f, 0.f, 0.f, 0.f};
        #pragma unroll
        for (int r = 0; r < 4; r++) { m_[r] = -1e30f; l_[r] = 0.0f; }
        #pragma unroll
        for (int d = 0; d < 4; d++) O[d] = zz;

        // prefetch K/V chunk 0 into registers
        bf16x8 kr0, kr1, vr0, vr1;
        {
            const u16* ks = qkv + (size_t)(b*T_ + 0 + rr)*3072 + 1024 + h*E_ + c;
            kr0 = *(const bf16x8*)(ks);
            kr1 = *(const bf16x8*)(ks + 8);
            const u16* vs = vT + (size_t)(bh*E_ + rr)*T_ + 0 + c;
            vr0 = *(const bf16x8*)(vs);
            vr1 = *(const bf16x8*)(vs + 8);
        }

        int nchunk = qt + 1;
        for (int ch = 0; ch < nchunk; ch++) {
            int j0 = ch * 64;
            __syncthreads();   // previous chunk's compute done -> LDS free
            // staged regs -> LDS (no global latency here)
            *(bf16x8*)&k_lds[rr*LS + c]     = kr0;
            *(bf16x8*)&k_lds[rr*LS + c + 8] = kr1;
            *(bf16x8*)&v_lds[rr*LS + c]     = vr0;
            *(bf16x8*)&v_lds[rr*LS + c + 8] = vr1;
            // issue next chunk's global loads; they complete under compute
            if (ch + 1 < nchunk) {
                int j1 = (ch + 1) * 64;
                const u16* ks = qkv + (size_t)(b*T_ + j1 + rr)*3072 + 1024 + h*E_ + c;
                kr0 = *(const bf16x8*)(ks);
                kr1 = *(const bf16x8*)(ks + 8);
                const u16* vs = vT + (size_t)(bh*E_ + rr)*T_ + j1 + c;
                vr0 = *(const bf16x8*)(vs);
                vr1 = *(const bf16x8*)(vs + 8);
            }
            __syncthreads();

            f32x4 S[4];
            #pragma unroll
            for (int nt = 0; nt < 4; nt++) {
                bf16x8 k0f = *(const bf16x8*)&k_lds[(nt*16 + l16)*LS + quad*8];
                bf16x8 k1f = *(const bf16x8*)&k_lds[(nt*16 + l16)*LS + 32 + quad*8];
                f32x4 z = zz;
                z = __builtin_amdgcn_mfma_f32_16x16x32_bf16(qf0, k0f, z, 0, 0, 0);
                z = __builtin_amdgcn_mfma_f32_16x16x32_bf16(qf1, k1f, z, 0, 0, 0);
                S[nt] = z;
            }
            int rowg = t0 + w*16 + quad*4;
            float P[4][4], mx[4];
            #pragma unroll
            for (int r = 0; r < 4; r++) mx[r] = -1e30f;
            #pragma unroll
            for (int nt = 0; nt < 4; nt++) {
                int colg = j0 + nt*16 + l16;
                #pragma unroll
                for (int r = 0; r < 4; r++) {
                    float s = S[nt][r] * 0.125f;
                    s = (colg > rowg + r) ? -1e30f : s;
                    P[nt][r] = s;
                    mx[r] = fmaxf(mx[r], s);
                }
            }
            #pragma unroll
            for (int o = 1; o < 16; o <<= 1)
                #pragma unroll
                for (int r = 0; r < 4; r++) mx[r] = fmaxf(mx[r], __shfl_xor(mx[r], o));
            float alpha[4], rsum[4];
            #pragma unroll
            for (int r = 0; r < 4; r++) {
                float mn = fmaxf(m_[r], mx[r]);
                alpha[r] = __expf(m_[r] - mn);
                m_[r] = mn;
                rsum[r] = 0.0f;
            }
            #pragma unroll
            for (int nt = 0; nt < 4; nt++)
                #pragma unroll
                for (int r = 0; r < 4; r++) {
                    float p = __expf(P[nt][r] - m_[r]);
                    P[nt][r] = p;
                    rsum[r] += p;
                }
            #pragma unroll
            for (int o = 1; o < 16; o <<= 1)
                #pragma unroll
                for (int r = 0; r < 4; r++) rsum[r] += __shfl_xor(rsum[r], o);
            #pragma unroll
            for (int r = 0; r < 4; r++) l_[r] = l_[r]*alpha[r] + rsum[r];
            #pragma unroll
            for (int d = 0; d < 4; d++)
                #pragma unroll
                for (int r = 0; r < 4; r++) O[d][r] *= alpha[r];

            #pragma unroll
            for (int nt = 0; nt < 4; nt++)
                #pragma unroll
                for (int r = 0; r < 4; r++)
                    p_lds[(w*16 + quad*4 + r)*LS + nt*16 + l16] = f2bf(P[nt][r]);
            bf16x8 pf0 = *(const bf16x8*)&p_lds[(w*16 + l16)*LS + quad*8];
            bf16x8 pf1 = *(const bf16x8*)&p_lds[(w*16 + l16)*LS + 32 + quad*8];
            #pragma unroll
            for (int d = 0; d < 4; d++) {
                bf16x8 v0f = *(const bf16x8*)&v_lds[(d*16 + l16)*LS + quad*8];
                bf16x8 v1f = *(const bf16x8*)&v_lds[(d*16 + l16)*LS + 32 + quad*8];
                O[d] = __builtin_amdgcn_mfma_f32_16x16x32_bf16(pf0, v0f, O[d], 0, 0, 0);
                O[d] = __builtin_amdgcn_mfma_f32_16x16x32_bf16(pf1, v1f, O[d], 0, 0, 0);
            }
        }

        #pragma unroll
        for (int r = 0; r < 4; r++) {
            float rl = 1.0f / l_[r];
            int tg = t0 + w*16 + quad*4 + r;
            #pragma unroll
            for (int d = 0; d < 4; d++)
                out[(size_t)(b*T_ + tg)*D_ + h*E_ + d*16 + l16] = f2bf(O[d][r] * rl);
        }
    }
}

extern "C" void kernel_launch(void* const* d_in, const int* in_sizes, int n_in,
                              void* d_out, int out_size, void* d_ws, size_t ws_size,
                              hipStream_t stream) {
    (void)in_sizes; (void)n_in; (void)out_size; (void)ws_size;
    const float* x      = (const float*)d_in[0];
    const float* wq     = (const float*)d_in[1];
    const float* wk     = (const float*)d_in[2];
    const float* wv     = (const float*)d_in[3];
    const float* w_proj = (const float*)d_in[4];
    const float* b_proj = (const float*)d_in[5];
    const float* w1     = (const float*)d_in[6];
    const float* b1     = (const float*)d_in[7];
    const float* w2     = (const float*)d_in[8];
    const float* b2     = (const float*)d_in[9];
    const float* g1     = (const float*)d_in[10];
    const float* be1    = (const float*)d_in[11];
    const float* g2     = (const float*)d_in[12];
    const float* be2    = (const float*)d_in[13];

    const size_t MB = 1024*1024;
    char* wsb = (char*)d_ws;
    u16* xn    = (u16*)(wsb + 0);          // 16MB  LN1(x) bf16
    u16* qkvb  = (u16*)(wsb + 16*MB);      // 48MB  [B*T,3072] q|k|v
    u16* h1    = (u16*)(wsb + 16*MB);      // 64MB  (reuses qkv+vT after attention)
    u16* vTb   = (u16*)(wsb + 64*MB);      // 16MB  [B*H*E, T]
    u16* attnb = (u16*)(wsb + 80*MB);      // 16MB  [B*T, D] concat heads
    u16* y1b   = (u16*)(wsb + 96*MB);      // 16MB  xn + proj out
    u16* xn2   = (u16*)(wsb + 112*MB);     // 16MB  LN2(y1)
    u16* WqkvT = (u16*)(wsb + 128*MB);     // 6MB   [3072,1024]
    u16* WprojT= (u16*)(wsb + 134*MB);     // 2MB   [1024,1024]
    u16* W1T   = (u16*)(wsb + 136*MB);     // 8MB   [4096,1024]
    u16* W2T   = (u16*)(wsb + 144*MB);     // 8MB   [1024,4096]  (ends at 152MB)

    // 1) LN1
    ln_f32_kernel<<<8192, 256, 0, stream>>>(x, g1, be1, xn);
    // 2) weights -> transposed bf16
    tcvt_qkv_kernel<<<dim3(1,16,48), 256, 0, stream>>>(wq, wk, wv, WqkvT);
    tcvt_kernel<<<dim3(16,16,1), 256, 0, stream>>>(w_proj, WprojT, 1024, 1024, 0, 0);
    tcvt_kernel<<<dim3(64,16,1), 256, 0, stream>>>(w1, W1T, 1024, 4096, 0, 0);
    tcvt_kernel<<<dim3(16,64,1), 256, 0, stream>>>(w2, W2T, 4096, 1024, 0, 0);
    // 3) QKV projection (fat 256x256)
    gemm_fat<<<dim3(12,32), 512, 0, stream>>>(xn, WqkvT, 8192, 3072, 1024,
                                              nullptr, nullptr, qkvb, 0);
    // 4) V -> [B,H,E,T]
    vtrans_kernel<<<dim3(16,128), 256, 0, stream>>>(qkvb, vTb);
    // 5) causal attention (paired tiles: 8 x 128 grid, 17 chunks/block)
    attn_kernel<<<dim3(8,128), 256, 0, stream>>>(qkvb, vTb, attnb);
    // 6) out projection + bias + residual(xn)  [residual uses NORMED x, faithful]
    gemm128<<<dim3(8,128), 256, 0, stream>>>(attnb, WprojT, 8192, 1024, 1024,
                                             b_proj, xn, y1b, 0);
    // 7) LN2
    ln_bf16_kernel<<<8192, 256, 0, stream>>>(y1b, g2, be2, xn2);
    // 8) FFN1 + bias + relu (fat 256x256)
    gemm_fat<<<dim3(16,32), 512, 0, stream>>>(xn2, W1T, 8192, 4096, 1024,
                                              b1, nullptr, h1, 1);
    // 9) FFN2 + bias + residual(xn2)  [residual uses NORMED y1, faithful] -> fp32 out
    gemm128<<<dim3(8,128), 256, 0, stream>>>(h1, W2T, 8192, 1024, 4096,
                                             b2, xn2, d_out, 2);
}

// Round 7
// 529.723 us; speedup vs baseline: 1.0219x; 1.0058x over previous
//
#include <hip/hip_runtime.h>
#include <stdint.h>

// Transformer block, bf16 MFMA implementation.
// B=8 T=1024 D=1024 H=16 E=64 F=4096.
#define B_ 8
#define T_ 1024
#define H_ 16
#define E_ 64
#define D_ 1024
#define F_ 4096

typedef unsigned short u16;
typedef __bf16 bf16x8 __attribute__((ext_vector_type(8)));
typedef float f32x4 __attribute__((ext_vector_type(4)));
typedef unsigned short u16x4 __attribute__((ext_vector_type(4)));

__device__ __forceinline__ u16 f2bf(float f) {
    unsigned int u = __builtin_bit_cast(unsigned int, f);
    u = (u + 0x7FFFu + ((u >> 16) & 1u)) >> 16;   // RNE
    return (u16)u;
}
__device__ __forceinline__ float bf2f(u16 h) {
    unsigned int u = ((unsigned int)h) << 16;
    return __builtin_bit_cast(float, u);
}

// async global->LDS DMA, 16B/lane; LDS dest = wave-uniform base + lane*16
__device__ __forceinline__ void async_b128(const u16* g, u16* l) {
    __builtin_amdgcn_global_load_lds(
        (const __attribute__((address_space(1))) void*)g,
        (__attribute__((address_space(3))) void*)l,
        16, 0, 0);
}

// ---------------- LayerNorm (fp32 in -> bf16 out) ----------------
__global__ __launch_bounds__(256) void ln_f32_kernel(const float* __restrict__ x,
        const float* __restrict__ g, const float* __restrict__ be, u16* __restrict__ out)
{
    int row = blockIdx.x, t = threadIdx.x;
    const float* xr = x + (size_t)row * D_;
    float4 v = ((const float4*)xr)[t];
    float s1 = v.x + v.y + v.z + v.w;
    float s2 = v.x*v.x + v.y*v.y + v.z*v.z + v.w*v.w;
    #pragma unroll
    for (int o = 32; o >= 1; o >>= 1) { s1 += __shfl_xor(s1, o); s2 += __shfl_xor(s2, o); }
    __shared__ float red[8];
    if ((t & 63) == 0) { red[(t>>6)*2] = s1; red[(t>>6)*2+1] = s2; }
    __syncthreads();
    s1 = red[0]+red[2]+red[4]+red[6];
    s2 = red[1]+red[3]+red[5]+red[7];
    float mu = s1 * (1.0f/D_);
    float rs = rsqrtf(s2*(1.0f/D_) - mu*mu + 1e-5f);
    float4 gv = ((const float4*)g)[t];
    float4 bv = ((const float4*)be)[t];
    u16 o0 = f2bf((v.x-mu)*rs*gv.x + bv.x);
    u16 o1 = f2bf((v.y-mu)*rs*gv.y + bv.y);
    u16 o2 = f2bf((v.z-mu)*rs*gv.z + bv.z);
    u16 o3 = f2bf((v.w-mu)*rs*gv.w + bv.w);
    uint2 pk; pk.x = (unsigned)o0 | ((unsigned)o1<<16); pk.y = (unsigned)o2 | ((unsigned)o3<<16);
    *(uint2*)(out + (size_t)row*D_ + t*4) = pk;
}

// ---------------- LayerNorm (bf16 in -> bf16 out) ----------------
__global__ __launch_bounds__(256) void ln_bf16_kernel(const u16* __restrict__ x,
        const float* __restrict__ g, const float* __restrict__ be, u16* __restrict__ out)
{
    int row = blockIdx.x, t = threadIdx.x;
    const u16* xr = x + (size_t)row * D_;
    u16x4 u = *(const u16x4*)(xr + t*4);
    float vx = bf2f(u.x), vy = bf2f(u.y), vz = bf2f(u.z), vw = bf2f(u.w);
    float s1 = vx + vy + vz + vw;
    float s2 = vx*vx + vy*vy + vz*vz + vw*vw;
    #pragma unroll
    for (int o = 32; o >= 1; o >>= 1) { s1 += __shfl_xor(s1, o); s2 += __shfl_xor(s2, o); }
    __shared__ float red[8];
    if ((t & 63) == 0) { red[(t>>6)*2] = s1; red[(t>>6)*2+1] = s2; }
    __syncthreads();
    s1 = red[0]+red[2]+red[4]+red[6];
    s2 = red[1]+red[3]+red[5]+red[7];
    float mu = s1 * (1.0f/D_);
    float rs = rsqrtf(s2*(1.0f/D_) - mu*mu + 1e-5f);
    float4 gv = ((const float4*)g)[t];
    float4 bv = ((const float4*)be)[t];
    u16 o0 = f2bf((vx-mu)*rs*gv.x + bv.x);
    u16 o1 = f2bf((vy-mu)*rs*gv.y + bv.y);
    u16 o2 = f2bf((vz-mu)*rs*gv.z + bv.z);
    u16 o3 = f2bf((vw-mu)*rs*gv.w + bv.w);
    uint2 pk; pk.x = (unsigned)o0 | ((unsigned)o1<<16); pk.y = (unsigned)o2 | ((unsigned)o3<<16);
    *(uint2*)(out + (size_t)row*D_ + t*4) = pk;
}

// ---------- transpose+convert fp32 [R,C] -> bf16 [C,R] (64x64 tiles) ----------
__global__ __launch_bounds__(256) void tcvt_kernel(const float* __restrict__ src,
        u16* __restrict__ dst, int R, int C, long sbatch, long dbatch)
{
    __shared__ float tile[64*65];
    int t = threadIdx.x;
    int c0 = blockIdx.x * 64, r0 = blockIdx.y * 64;
    const float* s = src + (long)blockIdx.z * sbatch;
    u16* d = dst + (long)blockIdx.z * dbatch;
    #pragma unroll
    for (int i = 0; i < 16; i++) {
        int e = t + i*256, rr = e >> 6, cc = e & 63;
        tile[rr*65 + cc] = s[(size_t)(r0+rr)*C + c0+cc];
    }
    __syncthreads();
    #pragma unroll
    for (int i = 0; i < 16; i++) {
        int e = t + i*256, rr = e >> 6, cc = e & 63;
        d[(size_t)(c0+rr)*R + r0+cc] = f2bf(tile[cc*65 + rr]);
    }
}

// ---------- QKV weights [H,1024,64] x3 -> bf16 [3072,1024] in ONE launch ----------
__global__ __launch_bounds__(256) void tcvt_qkv_kernel(const float* __restrict__ wq,
        const float* __restrict__ wk, const float* __restrict__ wv, u16* __restrict__ dst)
{
    __shared__ float tile[64*65];
    int t = threadIdx.x;
    int z = blockIdx.z;                 // 0..47
    int iw = z >> 4, h = z & 15;
    const float* s = (iw == 0 ? wq : (iw == 1 ? wk : wv)) + (long)h * 65536;
    u16* d = dst + (long)iw * (1024*1024) + (long)h * 64 * 1024;
    int r0 = blockIdx.y * 64;           // blockIdx.y in 0..15 (rows of the 1024)
    #pragma unroll
    for (int i = 0; i < 16; i++) {
        int e = t + i*256, rr = e >> 6, cc = e & 63;
        tile[rr*65 + cc] = s[(size_t)(r0+rr)*64 + cc];
    }
    __syncthreads();
    #pragma unroll
    for (int i = 0; i < 16; i++) {
        int e = t + i*256, rr = e >> 6, cc = e & 63;
        d[(size_t)rr*1024 + r0+cc] = f2bf(tile[cc*65 + rr]);
    }
}

// ---------- transpose V slice of qkv [B*T,3072] -> vT [B*H*E, T] (bf16) ----------
__global__ __launch_bounds__(256) void vtrans_kernel(const u16* __restrict__ qkv,
        u16* __restrict__ vT)
{
    __shared__ u16 tl[64*65];
    int t = threadIdx.x;
    int bh = blockIdx.y, b = bh >> 4, h = bh & 15;
    int t0 = blockIdx.x * 64;
    #pragma unroll
    for (int i = 0; i < 16; i++) {
        int e = t + i*256, rr = e >> 6, cc = e & 63;
        tl[rr*65 + cc] = qkv[(size_t)(b*T_ + t0 + rr)*3072 + 2048 + h*E_ + cc];
    }
    __syncthreads();
    #pragma unroll
    for (int i = 0; i < 16; i++) {
        int e = t + i*256, rr = e >> 6, cc = e & 63;
        vT[(size_t)(bh*E_ + rr)*T_ + t0 + cc] = tl[cc*65 + rr];
    }
}

// ---------------- bf16 MFMA GEMM:  C = A * Bt^T, 128x128 tile ----------------
// R7: resident-blocks model from R3/R6/m103 (us/block-iter = 0.295*(3/resident),
// tile-independent): keep 128^2 tile's FLOP/block-iter AND get 4 resident/CU.
//  (1) DOUBLE-buffer LDS (2x16KB = 32KB) with issue-AFTER-barrier:
//      vmcnt(0) [own slab-k loads landed] -> barrier [all waves' slab-k landed
//      AND compute(k-1) vacated buf (k+1)&1] -> issue slab k+1 -> compute k.
//  (2) Split-K via gridDim.z: kOff = z*kLen; when flags&4 write raw fp32
//      partials (z=0 -> out, z=1 -> out2), reduced by reduce_ffn2.
// Grid (8,64,KS); row-stripe XCD map (R3-proven FETCH 282->75MB).
// flags: 1=relu, 2=fp32 out, 4=fp32 raw partial (no bias/res/relu).
__global__ __launch_bounds__(256) void gemm128(
        const u16* __restrict__ A, const u16* __restrict__ Bt,
        int M, int N, int K, int kLen,
        const float* __restrict__ bias, const u16* __restrict__ res,
        void* __restrict__ out, void* __restrict__ out2, int flags)
{
    __shared__ __align__(16) u16 lA[2][128*32];
    __shared__ __align__(16) u16 lB[2][128*32];
    int t = threadIdx.x;
    int l = t & 63, l16 = l & 15, quad = l >> 4;
    int w = t >> 6, wm = w >> 1, wn = w & 1;

    // row-stripe XCD mapping (grid must be (8,64,z)): xcd == blockIdx.x
    int bm = blockIdx.x * 8 + (blockIdx.y & 7);
    int bn = blockIdx.y >> 3;
    long mBase = (long)bm * 128;
    long nBase = (long)bn * 128;
    int kOff = blockIdx.z * kLen;

    f32x4 zz = {0.f, 0.f, 0.f, 0.f};
    f32x4 acc[4][4];
    #pragma unroll
    for (int mt = 0; mt < 4; mt++)
        #pragma unroll
        for (int nt = 0; nt < 4; nt++) acc[mt][nt] = zz;

    int srow = l >> 2;
    int chunk = (l & 3) ^ ((l >> 3) & 3);
    const u16* gA0 = A  + (size_t)(mBase + w*32 +      srow) * K + kOff + chunk*8;
    const u16* gA1 = A  + (size_t)(mBase + w*32 + 16 + srow) * K + kOff + chunk*8;
    const u16* gB0 = Bt + (size_t)(nBase + w*32 +      srow) * K + kOff + chunk*8;
    const u16* gB1 = Bt + (size_t)(nBase + w*32 + 16 + srow) * K + kOff + chunk*8;
    int ldsOff0 = (w*32     )*32;
    int ldsOff1 = (w*32 + 16)*32;

    int fchunk = (quad ^ ((l16 >> 1) & 3)) * 8;
    int nIter = kLen >> 5;

    // prologue: slab 0 -> buffer 0
    async_b128(gA0, &lA[0][ldsOff0]);
    async_b128(gA1, &lA[0][ldsOff1]);
    async_b128(gB0, &lB[0][ldsOff0]);
    async_b128(gB1, &lB[0][ldsOff1]);

    for (int k = 0; k < nIter; k++) {
        int cur = k & 1, nxt = (k + 1) & 1;
        asm volatile("s_waitcnt vmcnt(0)" ::: "memory");   // own slab-k loads landed
        asm volatile("s_barrier" ::: "memory");            // all slab-k landed; buf nxt free
        if (k + 1 < nIter) {
            int koff = (k + 1) * 32;
            async_b128(gA0 + koff, &lA[nxt][ldsOff0]);
            async_b128(gA1 + koff, &lA[nxt][ldsOff1]);
            async_b128(gB0 + koff, &lB[nxt][ldsOff0]);
            async_b128(gB1 + koff, &lB[nxt][ldsOff1]);
        }
        bf16x8 af[4], bfr[4];
        #pragma unroll
        for (int mt = 0; mt < 4; mt++)
            af[mt] = *(const bf16x8*)&lA[cur][(wm*64 + mt*16 + l16)*32 + fchunk];
        #pragma unroll
        for (int nt = 0; nt < 4; nt++)
            bfr[nt] = *(const bf16x8*)&lB[cur][(wn*64 + nt*16 + l16)*32 + fchunk];
        #pragma unroll
        for (int mt = 0; mt < 4; mt++)
            #pragma unroll
            for (int nt = 0; nt < 4; nt++)
                acc[mt][nt] = __builtin_amdgcn_mfma_f32_16x16x32_bf16(af[mt], bfr[nt], acc[mt][nt], 0, 0, 0);
    }

    if (flags & 4) {
        // raw fp32 partial (split-K): z selects the partial buffer
        float* po = (float*)(blockIdx.z ? out2 : out);
        #pragma unroll
        for (int mt = 0; mt < 4; mt++)
            #pragma unroll
            for (int nt = 0; nt < 4; nt++) {
                long gn = nBase + wn*64 + nt*16 + l16;
                #pragma unroll
                for (int r = 0; r < 4; r++) {
                    long gm = mBase + wm*64 + mt*16 + quad*4 + r;
                    po[(size_t)gm*N + gn] = acc[mt][nt][r];
                }
            }
        return;
    }

    int do_relu = flags & 1, f32o = flags & 2;
    #pragma unroll
    for (int mt = 0; mt < 4; mt++) {
        #pragma unroll
        for (int nt = 0; nt < 4; nt++) {
            long gn = nBase + wn*64 + nt*16 + l16;
            float bv = bias ? bias[gn] : 0.0f;
            #pragma unroll
            for (int r = 0; r < 4; r++) {
                long gm = mBase + wm*64 + mt*16 + quad*4 + r;
                float v = acc[mt][nt][r] + bv;
                if (res) v += bf2f(res[(size_t)gm*N + gn]);
                if (do_relu) v = fmaxf(v, 0.0f);
                if (f32o) ((float*)out)[(size_t)gm*N + gn] = v;
                else      ((u16*)out)[(size_t)gm*N + gn] = f2bf(v);
            }
        }
    }
}

// ---- split-K fixup: out = P0 + P1(in place) + bias + residual (fp32 out) ----
__global__ __launch_bounds__(256) void reduce_ffn2(const float* __restrict__ P0,
        float* __restrict__ P1out, const float* __restrict__ bias,
        const u16* __restrict__ res)
{
    int row = blockIdx.x, t = threadIdx.x;
    size_t base = (size_t)row * D_ + t*4;
    float4 a = *(const float4*)(P0 + base);
    float4 b = *(const float4*)(P1out + base);
    float4 bb = *(const float4*)(bias + t*4);
    u16x4 r = *(const u16x4*)(res + base);
    float4 o;
    o.x = a.x + b.x + bb.x + bf2f(r.x);
    o.y = a.y + b.y + bb.y + bf2f(r.y);
    o.z = a.z + b.z + bb.z + bf2f(r.z);
    o.w = a.w + b.w + bb.w + bf2f(r.w);
    *(float4*)(P1out + base) = o;
}

// ---------------- FAT bf16 MFMA GEMM:  256x256 block, 512 thr ----------------
// 8 waves arranged 2(wm) x 4(wn); wave tile 128x64 (8 mt x 4 nt of 16x16x32).
// Triple-buffered slabs (3 x 32KB = 96KB, 1 block/CU, 2 waves/SIMD),
// depth-1 DMA prefetch, vmcnt(4), one raw barrier/iter (proven; UNCHANGED —
// VGPR (acc alone = 128) caps it at 1 block/CU anyway, so 2-buffer wouldn't
// raise residency).
__global__ __launch_bounds__(512, 2) void gemm_fat(
        const u16* __restrict__ A, const u16* __restrict__ Bt,
        int M, int N, int K,
        const float* __restrict__ bias, const u16* __restrict__ res,
        void* __restrict__ out, int flags)
{
    __shared__ __align__(16) u16 lA[3][256*32];
    __shared__ __align__(16) u16 lB[3][256*32];
    int t = threadIdx.x;
    int l = t & 63, l16 = l & 15, quad = l >> 4;
    int w = t >> 6;                 // 0..7
    int wm = w >> 2, wn = w & 3;    // 2 x 4
    long mBase = (long)blockIdx.y * 256;
    long nBase = (long)blockIdx.x * 256;

    f32x4 zz = {0.f, 0.f, 0.f, 0.f};
    f32x4 acc[8][4];
    #pragma unroll
    for (int mt = 0; mt < 8; mt++)
        #pragma unroll
        for (int nt = 0; nt < 4; nt++) acc[mt][nt] = zz;

    // staging: wave w covers rows w*32..w*32+31 of both A and B tiles (256 rows)
    int srow = l >> 2;
    int chunk = (l & 3) ^ ((l >> 3) & 3);
    const u16* gA0 = A  + (size_t)(mBase + w*32 +      srow) * K + chunk*8;
    const u16* gA1 = A  + (size_t)(mBase + w*32 + 16 + srow) * K + chunk*8;
    const u16* gB0 = Bt + (size_t)(nBase + w*32 +      srow) * K + chunk*8;
    const u16* gB1 = Bt + (size_t)(nBase + w*32 + 16 + srow) * K + chunk*8;
    int ldsOff0 = (w*32     )*32;
    int ldsOff1 = (w*32 + 16)*32;

    int fchunk = (quad ^ ((l16 >> 1) & 3)) * 8;
    int nIter = K >> 5;

    async_b128(gA0, &lA[0][ldsOff0]);
    async_b128(gA1, &lA[0][ldsOff1]);
    async_b128(gB0, &lB[0][ldsOff0]);
    async_b128(gB1, &lB[0][ldsOff1]);

    int cur = 0, nxt = 1;
    for (int k = 0; k < nIter; k++) {
        int koff = (k + 1 < nIter) ? (k + 1) * 32 : 0;
        async_b128(gA0 + koff, &lA[nxt][ldsOff0]);
        async_b128(gA1 + koff, &lA[nxt][ldsOff1]);
        async_b128(gB0 + koff, &lB[nxt][ldsOff0]);
        async_b128(gB1 + koff, &lB[nxt][ldsOff1]);
        asm volatile("s_waitcnt vmcnt(4)" ::: "memory");
        asm volatile("s_barrier" ::: "memory");
        bf16x8 bfr[4];
        #pragma unroll
        for (int nt = 0; nt < 4; nt++)
            bfr[nt] = *(const bf16x8*)&lB[cur][(wn*64 + nt*16 + l16)*32 + fchunk];
        #pragma unroll
        for (int mt = 0; mt < 8; mt++) {
            bf16x8 af = *(const bf16x8*)&lA[cur][(wm*128 + mt*16 + l16)*32 + fchunk];
            #pragma unroll
            for (int nt = 0; nt < 4; nt++)
                acc[mt][nt] = __builtin_amdgcn_mfma_f32_16x16x32_bf16(af, bfr[nt], acc[mt][nt], 0, 0, 0);
        }
        cur = nxt;
        nxt = nxt + 1; if (nxt == 3) nxt = 0;
    }

    int do_relu = flags & 1;
    #pragma unroll
    for (int mt = 0; mt < 8; mt++) {
        #pragma unroll
        for (int nt = 0; nt < 4; nt++) {
            long gn = nBase + wn*64 + nt*16 + l16;
            float bv = bias ? bias[gn] : 0.0f;
            #pragma unroll
            for (int r = 0; r < 4; r++) {
                long gm = mBase + wm*128 + mt*16 + quad*4 + r;
                float v = acc[mt][nt][r] + bv;
                if (do_relu) v = fmaxf(v, 0.0f);
                ((u16*)out)[(size_t)gm*N + gn] = f2bf(v);
            }
        }
    }
}

// ---------------- fused causal flash attention (bf16 MFMA) ----------------
// R3-proven: paired tiles (grid (8,128), block does q-tile a and 15-a ->
// exactly 17 chunks/block, zero tail imbalance) + T14 async-STAGE (next
// chunk's K/V global-loaded into regs during compute). UNCHANGED.
__global__ __launch_bounds__(256) void attn_kernel(
        const u16* __restrict__ qkv, const u16* __restrict__ vT, u16* __restrict__ out)
{
    constexpr int LS = 72;
    __shared__ __align__(16) u16 q_lds[64*LS];
    __shared__ __align__(16) u16 k_lds[64*LS];
    __shared__ __align__(16) u16 v_lds[64*LS];
    __shared__ __align__(16) u16 p_lds[64*LS];
    int t = threadIdx.x;
    int w = t >> 6, l = t & 63, l16 = l & 15, quad = l >> 4;
    int bh = blockIdx.y, b = bh >> 4, h = bh & 15;
    int rr = t >> 2, c = (t & 3) * 16;   // staging coords (64 rows x 64 cols)

    for (int pass = 0; pass < 2; pass++) {
        int qt = pass ? (15 - (int)blockIdx.x) : (int)blockIdx.x;
        int t0 = qt * 64;

        __syncthreads();   // protect q_lds/k/v reuse across passes
        {
            const u16* src = qkv + (size_t)(b*T_ + t0 + rr)*3072 + h*E_ + c;
            *(bf16x8*)&q_lds[rr*LS + c]     = *(const bf16x8*)(src);
            *(bf16x8*)&q_lds[rr*LS + c + 8] = *(const bf16x8*)(src + 8);
        }
        __syncthreads();
        bf16x8 qf0 = *(const bf16x8*)&q_lds[(w*16 + l16)*LS + quad*8];
        bf16x8 qf1 = *(const bf16x8*)&q_lds[(w*16 + l16)*LS + 32 + quad*8];

        float m_[4], l_[4];
        f32x4 O[4];
        f32x4 zz = {0.f, 0.f, 0.f, 0.f};
        #pragma unroll
        for (int r = 0; r < 4; r++) { m_[r] = -1e30f; l_[r] = 0.0f; }
        #pragma unroll
        for (int d = 0; d < 4; d++) O[d] = zz;

        // prefetch K/V chunk 0 into registers
        bf16x8 kr0, kr1, vr0, vr1;
        {
            const u16* ks = qkv + (size_t)(b*T_ + 0 + rr)*3072 + 1024 + h*E_ + c;
            kr0 = *(const bf16x8*)(ks);
            kr1 = *(const bf16x8*)(ks + 8);
            const u16* vs = vT + (size_t)(bh*E_ + rr)*T_ + 0 + c;
            vr0 = *(const bf16x8*)(vs);
            vr1 = *(const bf16x8*)(vs + 8);
        }

        int nchunk = qt + 1;
        for (int ch = 0; ch < nchunk; ch++) {
            int j0 = ch * 64;
            __syncthreads();   // previous chunk's compute done -> LDS free
            // staged regs -> LDS (no global latency here)
            *(bf16x8*)&k_lds[rr*LS + c]     = kr0;
            *(bf16x8*)&k_lds[rr*LS + c + 8] = kr1;
            *(bf16x8*)&v_lds[rr*LS + c]     = vr0;
            *(bf16x8*)&v_lds[rr*LS + c + 8] = vr1;
            // issue next chunk's global loads; they complete under compute
            if (ch + 1 < nchunk) {
                int j1 = (ch + 1) * 64;
                const u16* ks = qkv + (size_t)(b*T_ + j1 + rr)*3072 + 1024 + h*E_ + c;
                kr0 = *(const bf16x8*)(ks);
                kr1 = *(const bf16x8*)(ks + 8);
                const u16* vs = vT + (size_t)(bh*E_ + rr)*T_ + j1 + c;
                vr0 = *(const bf16x8*)(vs);
                vr1 = *(const bf16x8*)(vs + 8);
            }
            __syncthreads();

            f32x4 S[4];
            #pragma unroll
            for (int nt = 0; nt < 4; nt++) {
                bf16x8 k0f = *(const bf16x8*)&k_lds[(nt*16 + l16)*LS + quad*8];
                bf16x8 k1f = *(const bf16x8*)&k_lds[(nt*16 + l16)*LS + 32 + quad*8];
                f32x4 z = zz;
                z = __builtin_amdgcn_mfma_f32_16x16x32_bf16(qf0, k0f, z, 0, 0, 0);
                z = __builtin_amdgcn_mfma_f32_16x16x32_bf16(qf1, k1f, z, 0, 0, 0);
                S[nt] = z;
            }
            int rowg = t0 + w*16 + quad*4;
            float P[4][4], mx[4];
            #pragma unroll
            for (int r = 0; r < 4; r++) mx[r] = -1e30f;
            #pragma unroll
            for (int nt = 0; nt < 4; nt++) {
                int colg = j0 + nt*16 + l16;
                #pragma unroll
                for (int r = 0; r < 4; r++) {
                    float s = S[nt][r] * 0.125f;
                    s = (colg > rowg + r) ? -1e30f : s;
                    P[nt][r] = s;
                    mx[r] = fmaxf(mx[r], s);
                }
            }
            #pragma unroll
            for (int o = 1; o < 16; o <<= 1)
                #pragma unroll
                for (int r = 0; r < 4; r++) mx[r] = fmaxf(mx[r], __shfl_xor(mx[r], o));
            float alpha[4], rsum[4];
            #pragma unroll
            for (int r = 0; r < 4; r++) {
                float mn = fmaxf(m_[r], mx[r]);
                alpha[r] = __expf(m_[r] - mn);
                m_[r] = mn;
                rsum[r] = 0.0f;
            }
            #pragma unroll
            for (int nt = 0; nt < 4; nt++)
                #pragma unroll
                for (int r = 0; r < 4; r++) {
                    float p = __expf(P[nt][r] - m_[r]);
                    P[nt][r] = p;
                    rsum[r] += p;
                }
            #pragma unroll
            for (int o = 1; o < 16; o <<= 1)
                #pragma unroll
                for (int r = 0; r < 4; r++) rsum[r] += __shfl_xor(rsum[r], o);
            #pragma unroll
            for (int r = 0; r < 4; r++) l_[r] = l_[r]*alpha[r] + rsum[r];
            #pragma unroll
            for (int d = 0; d < 4; d++)
                #pragma unroll
                for (int r = 0; r < 4; r++) O[d][r] *= alpha[r];

            #pragma unroll
            for (int nt = 0; nt < 4; nt++)
                #pragma unroll
                for (int r = 0; r < 4; r++)
                    p_lds[(w*16 + quad*4 + r)*LS + nt*16 + l16] = f2bf(P[nt][r]);
            bf16x8 pf0 = *(const bf16x8*)&p_lds[(w*16 + l16)*LS + quad*8];
            bf16x8 pf1 = *(const bf16x8*)&p_lds[(w*16 + l16)*LS + 32 + quad*8];
            #pragma unroll
            for (int d = 0; d < 4; d++) {
                bf16x8 v0f = *(const bf16x8*)&v_lds[(d*16 + l16)*LS + quad*8];
                bf16x8 v1f = *(const bf16x8*)&v_lds[(d*16 + l16)*LS + 32 + quad*8];
                O[d] = __builtin_amdgcn_mfma_f32_16x16x32_bf16(pf0, v0f, O[d], 0, 0, 0);
                O[d] = __builtin_amdgcn_mfma_f32_16x16x32_bf16(pf1, v1f, O[d], 0, 0, 0);
            }
        }

        #pragma unroll
        for (int r = 0; r < 4; r++) {
            float rl = 1.0f / l_[r];
            int tg = t0 + w*16 + quad*4 + r;
            #pragma unroll
            for (int d = 0; d < 4; d++)
                out[(size_t)(b*T_ + tg)*D_ + h*E_ + d*16 + l16] = f2bf(O[d][r] * rl);
        }
    }
}

extern "C" void kernel_launch(void* const* d_in, const int* in_sizes, int n_in,
                              void* d_out, int out_size, void* d_ws, size_t ws_size,
                              hipStream_t stream) {
    (void)in_sizes; (void)n_in; (void)out_size; (void)ws_size;
    const float* x      = (const float*)d_in[0];
    const float* wq     = (const float*)d_in[1];
    const float* wk     = (const float*)d_in[2];
    const float* wv     = (const float*)d_in[3];
    const float* w_proj = (const float*)d_in[4];
    const float* b_proj = (const float*)d_in[5];
    const float* w1     = (const float*)d_in[6];
    const float* b1     = (const float*)d_in[7];
    const float* w2     = (const float*)d_in[8];
    const float* b2     = (const float*)d_in[9];
    const float* g1     = (const float*)d_in[10];
    const float* be1    = (const float*)d_in[11];
    const float* g2     = (const float*)d_in[12];
    const float* be2    = (const float*)d_in[13];

    const size_t MB = 1024*1024;
    char* wsb = (char*)d_ws;
    u16* xn    = (u16*)(wsb + 0);          // 16MB  LN1(x) bf16
    u16* qkvb  = (u16*)(wsb + 16*MB);      // 48MB  [B*T,3072] q|k|v
    u16* h1    = (u16*)(wsb + 16*MB);      // 64MB  (reuses qkv+vT after attention)
    u16* vTb   = (u16*)(wsb + 64*MB);      // 16MB  [B*H*E, T]
    u16* attnb = (u16*)(wsb + 80*MB);      // 16MB  [B*T, D] concat heads
    u16* y1b   = (u16*)(wsb + 96*MB);      // 16MB  xn + proj out
    u16* xn2   = (u16*)(wsb + 112*MB);     // 16MB  LN2(y1)
    u16* WqkvT = (u16*)(wsb + 128*MB);     // 6MB   [3072,1024]
    u16* WprojT= (u16*)(wsb + 134*MB);     // 2MB   [1024,1024]
    u16* W1T   = (u16*)(wsb + 136*MB);     // 8MB   [4096,1024]
    u16* W2T   = (u16*)(wsb + 144*MB);     // 8MB   [1024,4096]  (ends at 152MB)
    float* P0  = (float*)(wsb + 80*MB);    // 32MB  fp32 split-K partial (attnb+y1b
                                           //       region — both dead by FFN2 time)

    // 1) LN1
    ln_f32_kernel<<<8192, 256, 0, stream>>>(x, g1, be1, xn);
    // 2) weights -> transposed bf16
    tcvt_qkv_kernel<<<dim3(1,16,48), 256, 0, stream>>>(wq, wk, wv, WqkvT);
    tcvt_kernel<<<dim3(16,16,1), 256, 0, stream>>>(w_proj, WprojT, 1024, 1024, 0, 0);
    tcvt_kernel<<<dim3(64,16,1), 256, 0, stream>>>(w1, W1T, 1024, 4096, 0, 0);
    tcvt_kernel<<<dim3(16,64,1), 256, 0, stream>>>(w2, W2T, 4096, 1024, 0, 0);
    // 3) QKV projection (fat 256x256)
    gemm_fat<<<dim3(12,32), 512, 0, stream>>>(xn, WqkvT, 8192, 3072, 1024,
                                              nullptr, nullptr, qkvb, 0);
    // 4) V -> [B,H,E,T]
    vtrans_kernel<<<dim3(16,128), 256, 0, stream>>>(qkvb, vTb);
    // 5) causal attention (paired tiles: 8 x 128 grid, 17 chunks/block)
    attn_kernel<<<dim3(8,128), 256, 0, stream>>>(qkvb, vTb, attnb);
    // 6) out projection + bias + residual(xn)  [residual uses NORMED x, faithful]
    gemm128<<<dim3(8,64,1), 256, 0, stream>>>(attnb, WprojT, 8192, 1024, 1024, 1024,
                                              b_proj, xn, y1b, nullptr, 0);
    // 7) LN2
    ln_bf16_kernel<<<8192, 256, 0, stream>>>(y1b, g2, be2, xn2);
    // 8) FFN1 + bias + relu (fat 256x256)
    gemm_fat<<<dim3(16,32), 512, 0, stream>>>(xn2, W1T, 8192, 4096, 1024,
                                              b1, nullptr, h1, 1);
    // 9) FFN2 split-K=2: 1024 blocks = 4 resident/CU; fp32 partials
    //    z=0 -> P0, z=1 -> d_out; then reduce adds bias + residual(xn2)
    gemm128<<<dim3(8,64,2), 256, 0, stream>>>(h1, W2T, 8192, 1024, 4096, 2048,
                                              nullptr, nullptr, P0, d_out, 4);
    reduce_ffn2<<<8192, 256, 0, stream>>>(P0, (float*)d_out, b2, xn2);
}

// Round 8
// 512.043 us; speedup vs baseline: 1.0572x; 1.0345x over previous
//
#include <hip/hip_runtime.h>
#include <stdint.h>

// Transformer block, bf16 MFMA implementation.
// B=8 T=1024 D=1024 H=16 E=64 F=4096.
#define B_ 8
#define T_ 1024
#define H_ 16
#define E_ 64
#define D_ 1024
#define F_ 4096

typedef unsigned short u16;
typedef __bf16 bf16x8 __attribute__((ext_vector_type(8)));
typedef float f32x4 __attribute__((ext_vector_type(4)));
typedef unsigned short u16x4 __attribute__((ext_vector_type(4)));

__device__ __forceinline__ u16 f2bf(float f) {
    unsigned int u = __builtin_bit_cast(unsigned int, f);
    u = (u + 0x7FFFu + ((u >> 16) & 1u)) >> 16;   // RNE
    return (u16)u;
}
__device__ __forceinline__ float bf2f(u16 h) {
    unsigned int u = ((unsigned int)h) << 16;
    return __builtin_bit_cast(float, u);
}

// async global->LDS DMA, 16B/lane; LDS dest = wave-uniform base + lane*16
__device__ __forceinline__ void async_b128(const u16* g, u16* l) {
    __builtin_amdgcn_global_load_lds(
        (const __attribute__((address_space(1))) void*)g,
        (__attribute__((address_space(3))) void*)l,
        16, 0, 0);
}

// ---------------- LayerNorm (fp32 in -> bf16 out) ----------------
__global__ __launch_bounds__(256) void ln_f32_kernel(const float* __restrict__ x,
        const float* __restrict__ g, const float* __restrict__ be, u16* __restrict__ out)
{
    int row = blockIdx.x, t = threadIdx.x;
    const float* xr = x + (size_t)row * D_;
    float4 v = ((const float4*)xr)[t];
    float s1 = v.x + v.y + v.z + v.w;
    float s2 = v.x*v.x + v.y*v.y + v.z*v.z + v.w*v.w;
    #pragma unroll
    for (int o = 32; o >= 1; o >>= 1) { s1 += __shfl_xor(s1, o); s2 += __shfl_xor(s2, o); }
    __shared__ float red[8];
    if ((t & 63) == 0) { red[(t>>6)*2] = s1; red[(t>>6)*2+1] = s2; }
    __syncthreads();
    s1 = red[0]+red[2]+red[4]+red[6];
    s2 = red[1]+red[3]+red[5]+red[7];
    float mu = s1 * (1.0f/D_);
    float rs = rsqrtf(s2*(1.0f/D_) - mu*mu + 1e-5f);
    float4 gv = ((const float4*)g)[t];
    float4 bv = ((const float4*)be)[t];
    u16 o0 = f2bf((v.x-mu)*rs*gv.x + bv.x);
    u16 o1 = f2bf((v.y-mu)*rs*gv.y + bv.y);
    u16 o2 = f2bf((v.z-mu)*rs*gv.z + bv.z);
    u16 o3 = f2bf((v.w-mu)*rs*gv.w + bv.w);
    uint2 pk; pk.x = (unsigned)o0 | ((unsigned)o1<<16); pk.y = (unsigned)o2 | ((unsigned)o3<<16);
    *(uint2*)(out + (size_t)row*D_ + t*4) = pk;
}

// ---------------- LayerNorm (bf16 in -> bf16 out) ----------------
__global__ __launch_bounds__(256) void ln_bf16_kernel(const u16* __restrict__ x,
        const float* __restrict__ g, const float* __restrict__ be, u16* __restrict__ out)
{
    int row = blockIdx.x, t = threadIdx.x;
    const u16* xr = x + (size_t)row * D_;
    u16x4 u = *(const u16x4*)(xr + t*4);
    float vx = bf2f(u.x), vy = bf2f(u.y), vz = bf2f(u.z), vw = bf2f(u.w);
    float s1 = vx + vy + vz + vw;
    float s2 = vx*vx + vy*vy + vz*vz + vw*vw;
    #pragma unroll
    for (int o = 32; o >= 1; o >>= 1) { s1 += __shfl_xor(s1, o); s2 += __shfl_xor(s2, o); }
    __shared__ float red[8];
    if ((t & 63) == 0) { red[(t>>6)*2] = s1; red[(t>>6)*2+1] = s2; }
    __syncthreads();
    s1 = red[0]+red[2]+red[4]+red[6];
    s2 = red[1]+red[3]+red[5]+red[7];
    float mu = s1 * (1.0f/D_);
    float rs = rsqrtf(s2*(1.0f/D_) - mu*mu + 1e-5f);
    float4 gv = ((const float4*)g)[t];
    float4 bv = ((const float4*)be)[t];
    u16 o0 = f2bf((vx-mu)*rs*gv.x + bv.x);
    u16 o1 = f2bf((vy-mu)*rs*gv.y + bv.y);
    u16 o2 = f2bf((vz-mu)*rs*gv.z + bv.z);
    u16 o3 = f2bf((vw-mu)*rs*gv.w + bv.w);
    uint2 pk; pk.x = (unsigned)o0 | ((unsigned)o1<<16); pk.y = (unsigned)o2 | ((unsigned)o3<<16);
    *(uint2*)(out + (size_t)row*D_ + t*4) = pk;
}

// ---------- transpose+convert fp32 [R,C] -> bf16 [C,R] (64x64 tiles) ----------
__global__ __launch_bounds__(256) void tcvt_kernel(const float* __restrict__ src,
        u16* __restrict__ dst, int R, int C, long sbatch, long dbatch)
{
    __shared__ float tile[64*65];
    int t = threadIdx.x;
    int c0 = blockIdx.x * 64, r0 = blockIdx.y * 64;
    const float* s = src + (long)blockIdx.z * sbatch;
    u16* d = dst + (long)blockIdx.z * dbatch;
    #pragma unroll
    for (int i = 0; i < 16; i++) {
        int e = t + i*256, rr = e >> 6, cc = e & 63;
        tile[rr*65 + cc] = s[(size_t)(r0+rr)*C + c0+cc];
    }
    __syncthreads();
    #pragma unroll
    for (int i = 0; i < 16; i++) {
        int e = t + i*256, rr = e >> 6, cc = e & 63;
        d[(size_t)(c0+rr)*R + r0+cc] = f2bf(tile[cc*65 + rr]);
    }
}

// ---------- QKV weights [H,1024,64] x3 -> bf16 [3072,1024] in ONE launch ----------
__global__ __launch_bounds__(256) void tcvt_qkv_kernel(const float* __restrict__ wq,
        const float* __restrict__ wk, const float* __restrict__ wv, u16* __restrict__ dst)
{
    __shared__ float tile[64*65];
    int t = threadIdx.x;
    int z = blockIdx.z;                 // 0..47
    int iw = z >> 4, h = z & 15;
    const float* s = (iw == 0 ? wq : (iw == 1 ? wk : wv)) + (long)h * 65536;
    u16* d = dst + (long)iw * (1024*1024) + (long)h * 64 * 1024;
    int r0 = blockIdx.y * 64;           // blockIdx.y in 0..15 (rows of the 1024)
    #pragma unroll
    for (int i = 0; i < 16; i++) {
        int e = t + i*256, rr = e >> 6, cc = e & 63;
        tile[rr*65 + cc] = s[(size_t)(r0+rr)*64 + cc];
    }
    __syncthreads();
    #pragma unroll
    for (int i = 0; i < 16; i++) {
        int e = t + i*256, rr = e >> 6, cc = e & 63;
        d[(size_t)rr*1024 + r0+cc] = f2bf(tile[cc*65 + rr]);
    }
}

// ---------- transpose V slice of qkv [B*T,3072] -> vT [B*H*E, T] (bf16) ----------
__global__ __launch_bounds__(256) void vtrans_kernel(const u16* __restrict__ qkv,
        u16* __restrict__ vT)
{
    __shared__ u16 tl[64*65];
    int t = threadIdx.x;
    int bh = blockIdx.y, b = bh >> 4, h = bh & 15;
    int t0 = blockIdx.x * 64;
    #pragma unroll
    for (int i = 0; i < 16; i++) {
        int e = t + i*256, rr = e >> 6, cc = e & 63;
        tl[rr*65 + cc] = qkv[(size_t)(b*T_ + t0 + rr)*3072 + 2048 + h*E_ + cc];
    }
    __syncthreads();
    #pragma unroll
    for (int i = 0; i < 16; i++) {
        int e = t + i*256, rr = e >> 6, cc = e & 63;
        vT[(size_t)(bh*E_ + rr)*T_ + t0 + cc] = tl[cc*65 + rr];
    }
}

// ---------------- bf16 MFMA GEMM:  C = A * Bt^T, 128x128 tile ----------------
// General version (used for PROJ, grid (8,64,1) = 2 resident by grid anyway).
// Double-buffer LDS, issue-after-barrier, vmcnt(0). Row-stripe XCD map.
// flags: 1=relu, 2=fp32 out, 4=fp32 raw partial (no bias/res/relu).
__global__ __launch_bounds__(256) void gemm128(
        const u16* __restrict__ A, const u16* __restrict__ Bt,
        int M, int N, int K, int kLen,
        const float* __restrict__ bias, const u16* __restrict__ res,
        void* __restrict__ out, void* __restrict__ out2, int flags)
{
    __shared__ __align__(16) u16 lA[2][128*32];
    __shared__ __align__(16) u16 lB[2][128*32];
    int t = threadIdx.x;
    int l = t & 63, l16 = l & 15, quad = l >> 4;
    int w = t >> 6, wm = w >> 1, wn = w & 1;

    int bm = blockIdx.x * 8 + (blockIdx.y & 7);
    int bn = blockIdx.y >> 3;
    long mBase = (long)bm * 128;
    long nBase = (long)bn * 128;
    int kOff = blockIdx.z * kLen;

    f32x4 zz = {0.f, 0.f, 0.f, 0.f};
    f32x4 acc[4][4];
    #pragma unroll
    for (int mt = 0; mt < 4; mt++)
        #pragma unroll
        for (int nt = 0; nt < 4; nt++) acc[mt][nt] = zz;

    int srow = l >> 2;
    int chunk = (l & 3) ^ ((l >> 3) & 3);
    const u16* gA0 = A  + (size_t)(mBase + w*32 +      srow) * K + kOff + chunk*8;
    const u16* gA1 = A  + (size_t)(mBase + w*32 + 16 + srow) * K + kOff + chunk*8;
    const u16* gB0 = Bt + (size_t)(nBase + w*32 +      srow) * K + kOff + chunk*8;
    const u16* gB1 = Bt + (size_t)(nBase + w*32 + 16 + srow) * K + kOff + chunk*8;
    int ldsOff0 = (w*32     )*32;
    int ldsOff1 = (w*32 + 16)*32;

    int fchunk = (quad ^ ((l16 >> 1) & 3)) * 8;
    int nIter = kLen >> 5;

    async_b128(gA0, &lA[0][ldsOff0]);
    async_b128(gA1, &lA[0][ldsOff1]);
    async_b128(gB0, &lB[0][ldsOff0]);
    async_b128(gB1, &lB[0][ldsOff1]);

    for (int k = 0; k < nIter; k++) {
        int cur = k & 1, nxt = (k + 1) & 1;
        asm volatile("s_waitcnt vmcnt(0)" ::: "memory");
        asm volatile("s_barrier" ::: "memory");
        if (k + 1 < nIter) {
            int koff = (k + 1) * 32;
            async_b128(gA0 + koff, &lA[nxt][ldsOff0]);
            async_b128(gA1 + koff, &lA[nxt][ldsOff1]);
            async_b128(gB0 + koff, &lB[nxt][ldsOff0]);
            async_b128(gB1 + koff, &lB[nxt][ldsOff1]);
        }
        bf16x8 af[4], bfr[4];
        #pragma unroll
        for (int mt = 0; mt < 4; mt++)
            af[mt] = *(const bf16x8*)&lA[cur][(wm*64 + mt*16 + l16)*32 + fchunk];
        #pragma unroll
        for (int nt = 0; nt < 4; nt++)
            bfr[nt] = *(const bf16x8*)&lB[cur][(wn*64 + nt*16 + l16)*32 + fchunk];
        #pragma unroll
        for (int mt = 0; mt < 4; mt++)
            #pragma unroll
            for (int nt = 0; nt < 4; nt++)
                acc[mt][nt] = __builtin_amdgcn_mfma_f32_16x16x32_bf16(af[mt], bfr[nt], acc[mt][nt], 0, 0, 0);
    }

    if (flags & 4) {
        float* po = (float*)(blockIdx.z ? out2 : out);
        #pragma unroll
        for (int mt = 0; mt < 4; mt++)
            #pragma unroll
            for (int nt = 0; nt < 4; nt++) {
                long gn = nBase + wn*64 + nt*16 + l16;
                #pragma unroll
                for (int r = 0; r < 4; r++) {
                    long gm = mBase + wm*64 + mt*16 + quad*4 + r;
                    po[(size_t)gm*N + gn] = acc[mt][nt][r];
                }
            }
        return;
    }

    int do_relu = flags & 1, f32o = flags & 2;
    #pragma unroll
    for (int mt = 0; mt < 4; mt++) {
        #pragma unroll
        for (int nt = 0; nt < 4; nt++) {
            long gn = nBase + wn*64 + nt*16 + l16;
            float bv = bias ? bias[gn] : 0.0f;
            #pragma unroll
            for (int r = 0; r < 4; r++) {
                long gm = mBase + wm*64 + mt*16 + quad*4 + r;
                float v = acc[mt][nt][r] + bv;
                if (res) v += bf2f(res[(size_t)gm*N + gn]);
                if (do_relu) v = fmaxf(v, 0.0f);
                if (f32o) ((float*)out)[(size_t)gm*N + gn] = v;
                else      ((u16*)out)[(size_t)gm*N + gn] = f2bf(v);
            }
        }
    }
}

// ------- FFN2 split-K GEMM, register-dieted for 4 blocks/CU residency -------
// R8 theory: R7's 23% occupancy = unified-RF cap (76 arch + 64 acc = 140 >
// 128 -> 2-3 waves/SIMD). __launch_bounds__(256,4) forces total <=128/wave
// -> 4 blocks/CU. Diet: hardcoded geometry (K=4096, N=1024, kLen=2048 ->
// address math folds to SGPR), af loaded per-mt (1 live A-frag, not 4),
// no flag branches, raw fp32 partial epilogue. Grid (8,64,2); 2-buffer
// 32KB LDS; row-stripe XCD map.
__global__ __launch_bounds__(256, 4) void gemm_sk(
        const u16* __restrict__ A, const u16* __restrict__ Bt,
        float* __restrict__ out0, float* __restrict__ out1)
{
    __shared__ __align__(16) u16 lA[2][128*32];
    __shared__ __align__(16) u16 lB[2][128*32];
    int t = threadIdx.x;
    int l = t & 63, l16 = l & 15, quad = l >> 4;
    int w = t >> 6, wm = w >> 1, wn = w & 1;

    int bm = blockIdx.x * 8 + (blockIdx.y & 7);
    int bn = blockIdx.y >> 3;
    long mBase = (long)bm * 128;
    long nBase = (long)bn * 128;
    int kOff = blockIdx.z * 2048;

    f32x4 zz = {0.f, 0.f, 0.f, 0.f};
    f32x4 acc[4][4];
    #pragma unroll
    for (int mt = 0; mt < 4; mt++)
        #pragma unroll
        for (int nt = 0; nt < 4; nt++) acc[mt][nt] = zz;

    int srow = l >> 2;
    int chunk = (l & 3) ^ ((l >> 3) & 3);
    const u16* gA0 = A  + (size_t)(mBase + w*32 +      srow) * 4096 + kOff + chunk*8;
    const u16* gA1 = A  + (size_t)(mBase + w*32 + 16 + srow) * 4096 + kOff + chunk*8;
    const u16* gB0 = Bt + (size_t)(nBase + w*32 +      srow) * 4096 + kOff + chunk*8;
    const u16* gB1 = Bt + (size_t)(nBase + w*32 + 16 + srow) * 4096 + kOff + chunk*8;
    int ldsOff0 = (w*32     )*32;
    int ldsOff1 = (w*32 + 16)*32;

    int fchunk = (quad ^ ((l16 >> 1) & 3)) * 8;

    async_b128(gA0, &lA[0][ldsOff0]);
    async_b128(gA1, &lA[0][ldsOff1]);
    async_b128(gB0, &lB[0][ldsOff0]);
    async_b128(gB1, &lB[0][ldsOff1]);

    for (int k = 0; k < 64; k++) {
        int cur = k & 1, nxt = (k + 1) & 1;
        asm volatile("s_waitcnt vmcnt(0)" ::: "memory");
        asm volatile("s_barrier" ::: "memory");
        if (k + 1 < 64) {
            int koff = (k + 1) * 32;
            async_b128(gA0 + koff, &lA[nxt][ldsOff0]);
            async_b128(gA1 + koff, &lA[nxt][ldsOff1]);
            async_b128(gB0 + koff, &lB[nxt][ldsOff0]);
            async_b128(gB1 + koff, &lB[nxt][ldsOff1]);
        }
        bf16x8 bfr[4];
        #pragma unroll
        for (int nt = 0; nt < 4; nt++)
            bfr[nt] = *(const bf16x8*)&lB[cur][(wn*64 + nt*16 + l16)*32 + fchunk];
        #pragma unroll
        for (int mt = 0; mt < 4; mt++) {
            bf16x8 af = *(const bf16x8*)&lA[cur][(wm*64 + mt*16 + l16)*32 + fchunk];
            #pragma unroll
            for (int nt = 0; nt < 4; nt++)
                acc[mt][nt] = __builtin_amdgcn_mfma_f32_16x16x32_bf16(af, bfr[nt], acc[mt][nt], 0, 0, 0);
        }
    }

    float* po = blockIdx.z ? out1 : out0;
    #pragma unroll
    for (int mt = 0; mt < 4; mt++)
        #pragma unroll
        for (int nt = 0; nt < 4; nt++) {
            long gn = nBase + wn*64 + nt*16 + l16;
            #pragma unroll
            for (int r = 0; r < 4; r++) {
                long gm = mBase + wm*64 + mt*16 + quad*4 + r;
                po[(size_t)gm*1024 + gn] = acc[mt][nt][r];
            }
        }
}

// ---- split-K fixup: out = P0 + P1(in place) + bias + residual (fp32 out) ----
__global__ __launch_bounds__(256) void reduce_ffn2(const float* __restrict__ P0,
        float* __restrict__ P1out, const float* __restrict__ bias,
        const u16* __restrict__ res)
{
    int row = blockIdx.x, t = threadIdx.x;
    size_t base = (size_t)row * D_ + t*4;
    float4 a = *(const float4*)(P0 + base);
    float4 b = *(const float4*)(P1out + base);
    float4 bb = *(const float4*)(bias + t*4);
    u16x4 r = *(const u16x4*)(res + base);
    float4 o;
    o.x = a.x + b.x + bb.x + bf2f(r.x);
    o.y = a.y + b.y + bb.y + bf2f(r.y);
    o.z = a.z + b.z + bb.z + bf2f(r.z);
    o.w = a.w + b.w + bb.w + bf2f(r.w);
    *(float4*)(P1out + base) = o;
}

// ---------------- FAT bf16 MFMA GEMM:  256x256 block, 512 thr ----------------
// 8 waves arranged 2(wm) x 4(wn); wave tile 128x64 (8 mt x 4 nt of 16x16x32).
// Triple-buffered slabs (3 x 32KB = 96KB, 1 block/CU, 2 waves/SIMD),
// depth-1 DMA prefetch, vmcnt(4), one raw barrier/iter (proven; UNCHANGED).
__global__ __launch_bounds__(512, 2) void gemm_fat(
        const u16* __restrict__ A, const u16* __restrict__ Bt,
        int M, int N, int K,
        const float* __restrict__ bias, const u16* __restrict__ res,
        void* __restrict__ out, int flags)
{
    __shared__ __align__(16) u16 lA[3][256*32];
    __shared__ __align__(16) u16 lB[3][256*32];
    int t = threadIdx.x;
    int l = t & 63, l16 = l & 15, quad = l >> 4;
    int w = t >> 6;                 // 0..7
    int wm = w >> 2, wn = w & 3;    // 2 x 4
    long mBase = (long)blockIdx.y * 256;
    long nBase = (long)blockIdx.x * 256;

    f32x4 zz = {0.f, 0.f, 0.f, 0.f};
    f32x4 acc[8][4];
    #pragma unroll
    for (int mt = 0; mt < 8; mt++)
        #pragma unroll
        for (int nt = 0; nt < 4; nt++) acc[mt][nt] = zz;

    int srow = l >> 2;
    int chunk = (l & 3) ^ ((l >> 3) & 3);
    const u16* gA0 = A  + (size_t)(mBase + w*32 +      srow) * K + chunk*8;
    const u16* gA1 = A  + (size_t)(mBase + w*32 + 16 + srow) * K + chunk*8;
    const u16* gB0 = Bt + (size_t)(nBase + w*32 +      srow) * K + chunk*8;
    const u16* gB1 = Bt + (size_t)(nBase + w*32 + 16 + srow) * K + chunk*8;
    int ldsOff0 = (w*32     )*32;
    int ldsOff1 = (w*32 + 16)*32;

    int fchunk = (quad ^ ((l16 >> 1) & 3)) * 8;
    int nIter = K >> 5;

    async_b128(gA0, &lA[0][ldsOff0]);
    async_b128(gA1, &lA[0][ldsOff1]);
    async_b128(gB0, &lB[0][ldsOff0]);
    async_b128(gB1, &lB[0][ldsOff1]);

    int cur = 0, nxt = 1;
    for (int k = 0; k < nIter; k++) {
        int koff = (k + 1 < nIter) ? (k + 1) * 32 : 0;
        async_b128(gA0 + koff, &lA[nxt][ldsOff0]);
        async_b128(gA1 + koff, &lA[nxt][ldsOff1]);
        async_b128(gB0 + koff, &lB[nxt][ldsOff0]);
        async_b128(gB1 + koff, &lB[nxt][ldsOff1]);
        asm volatile("s_waitcnt vmcnt(4)" ::: "memory");
        asm volatile("s_barrier" ::: "memory");
        bf16x8 bfr[4];
        #pragma unroll
        for (int nt = 0; nt < 4; nt++)
            bfr[nt] = *(const bf16x8*)&lB[cur][(wn*64 + nt*16 + l16)*32 + fchunk];
        #pragma unroll
        for (int mt = 0; mt < 8; mt++) {
            bf16x8 af = *(const bf16x8*)&lA[cur][(wm*128 + mt*16 + l16)*32 + fchunk];
            #pragma unroll
            for (int nt = 0; nt < 4; nt++)
                acc[mt][nt] = __builtin_amdgcn_mfma_f32_16x16x32_bf16(af, bfr[nt], acc[mt][nt], 0, 0, 0);
        }
        cur = nxt;
        nxt = nxt + 1; if (nxt == 3) nxt = 0;
    }

    int do_relu = flags & 1;
    #pragma unroll
    for (int mt = 0; mt < 8; mt++) {
        #pragma unroll
        for (int nt = 0; nt < 4; nt++) {
            long gn = nBase + wn*64 + nt*16 + l16;
            float bv = bias ? bias[gn] : 0.0f;
            #pragma unroll
            for (int r = 0; r < 4; r++) {
                long gm = mBase + wm*128 + mt*16 + quad*4 + r;
                float v = acc[mt][nt][r] + bv;
                if (do_relu) v = fmaxf(v, 0.0f);
                ((u16*)out)[(size_t)gm*N + gn] = f2bf(v);
            }
        }
    }
}

// ---------------- fused causal flash attention (bf16 MFMA) ----------------
// R3-proven: paired tiles (grid (8,128), block does q-tile a and 15-a ->
// exactly 17 chunks/block, zero tail imbalance) + T14 async-STAGE (next
// chunk's K/V global-loaded into regs during compute). UNCHANGED.
__global__ __launch_bounds__(256) void attn_kernel(
        const u16* __restrict__ qkv, const u16* __restrict__ vT, u16* __restrict__ out)
{
    constexpr int LS = 72;
    __shared__ __align__(16) u16 q_lds[64*LS];
    __shared__ __align__(16) u16 k_lds[64*LS];
    __shared__ __align__(16) u16 v_lds[64*LS];
    __shared__ __align__(16) u16 p_lds[64*LS];
    int t = threadIdx.x;
    int w = t >> 6, l = t & 63, l16 = l & 15, quad = l >> 4;
    int bh = blockIdx.y, b = bh >> 4, h = bh & 15;
    int rr = t >> 2, c = (t & 3) * 16;   // staging coords (64 rows x 64 cols)

    for (int pass = 0; pass < 2; pass++) {
        int qt = pass ? (15 - (int)blockIdx.x) : (int)blockIdx.x;
        int t0 = qt * 64;

        __syncthreads();   // protect q_lds/k/v reuse across passes
        {
            const u16* src = qkv + (size_t)(b*T_ + t0 + rr)*3072 + h*E_ + c;
            *(bf16x8*)&q_lds[rr*LS + c]     = *(const bf16x8*)(src);
            *(bf16x8*)&q_lds[rr*LS + c + 8] = *(const bf16x8*)(src + 8);
        }
        __syncthreads();
        bf16x8 qf0 = *(const bf16x8*)&q_lds[(w*16 + l16)*LS + quad*8];
        bf16x8 qf1 = *(const bf16x8*)&q_lds[(w*16 + l16)*LS + 32 + quad*8];

        float m_[4], l_[4];
        f32x4 O[4];
        f32x4 zz = {0.f, 0.f, 0.f, 0.f};
        #pragma unroll
        for (int r = 0; r < 4; r++) { m_[r] = -1e30f; l_[r] = 0.0f; }
        #pragma unroll
        for (int d = 0; d < 4; d++) O[d] = zz;

        // prefetch K/V chunk 0 into registers
        bf16x8 kr0, kr1, vr0, vr1;
        {
            const u16* ks = qkv + (size_t)(b*T_ + 0 + rr)*3072 + 1024 + h*E_ + c;
            kr0 = *(const bf16x8*)(ks);
            kr1 = *(const bf16x8*)(ks + 8);
            const u16* vs = vT + (size_t)(bh*E_ + rr)*T_ + 0 + c;
            vr0 = *(const bf16x8*)(vs);
            vr1 = *(const bf16x8*)(vs + 8);
        }

        int nchunk = qt + 1;
        for (int ch = 0; ch < nchunk; ch++) {
            int j0 = ch * 64;
            __syncthreads();   // previous chunk's compute done -> LDS free
            // staged regs -> LDS (no global latency here)
            *(bf16x8*)&k_lds[rr*LS + c]     = kr0;
            *(bf16x8*)&k_lds[rr*LS + c + 8] = kr1;
            *(bf16x8*)&v_lds[rr*LS + c]     = vr0;
            *(bf16x8*)&v_lds[rr*LS + c + 8] = vr1;
            // issue next chunk's global loads; they complete under compute
            if (ch + 1 < nchunk) {
                int j1 = (ch + 1) * 64;
                const u16* ks = qkv + (size_t)(b*T_ + j1 + rr)*3072 + 1024 + h*E_ + c;
                kr0 = *(const bf16x8*)(ks);
                kr1 = *(const bf16x8*)(ks + 8);
                const u16* vs = vT + (size_t)(bh*E_ + rr)*T_ + j1 + c;
                vr0 = *(const bf16x8*)(vs);
                vr1 = *(const bf16x8*)(vs + 8);
            }
            __syncthreads();

            f32x4 S[4];
            #pragma unroll
            for (int nt = 0; nt < 4; nt++) {
                bf16x8 k0f = *(const bf16x8*)&k_lds[(nt*16 + l16)*LS + quad*8];
                bf16x8 k1f = *(const bf16x8*)&k_lds[(nt*16 + l16)*LS + 32 + quad*8];
                f32x4 z = zz;
                z = __builtin_amdgcn_mfma_f32_16x16x32_bf16(qf0, k0f, z, 0, 0, 0);
                z = __builtin_amdgcn_mfma_f32_16x16x32_bf16(qf1, k1f, z, 0, 0, 0);
                S[nt] = z;
            }
            int rowg = t0 + w*16 + quad*4;
            float P[4][4], mx[4];
            #pragma unroll
            for (int r = 0; r < 4; r++) mx[r] = -1e30f;
            #pragma unroll
            for (int nt = 0; nt < 4; nt++) {
                int colg = j0 + nt*16 + l16;
                #pragma unroll
                for (int r = 0; r < 4; r++) {
                    float s = S[nt][r] * 0.125f;
                    s = (colg > rowg + r) ? -1e30f : s;
                    P[nt][r] = s;
                    mx[r] = fmaxf(mx[r], s);
                }
            }
            #pragma unroll
            for (int o = 1; o < 16; o <<= 1)
                #pragma unroll
                for (int r = 0; r < 4; r++) mx[r] = fmaxf(mx[r], __shfl_xor(mx[r], o));
            float alpha[4], rsum[4];
            #pragma unroll
            for (int r = 0; r < 4; r++) {
                float mn = fmaxf(m_[r], mx[r]);
                alpha[r] = __expf(m_[r] - mn);
                m_[r] = mn;
                rsum[r] = 0.0f;
            }
            #pragma unroll
            for (int nt = 0; nt < 4; nt++)
                #pragma unroll
                for (int r = 0; r < 4; r++) {
                    float p = __expf(P[nt][r] - m_[r]);
                    P[nt][r] = p;
                    rsum[r] += p;
                }
            #pragma unroll
            for (int o = 1; o < 16; o <<= 1)
                #pragma unroll
                for (int r = 0; r < 4; r++) rsum[r] += __shfl_xor(rsum[r], o);
            #pragma unroll
            for (int r = 0; r < 4; r++) l_[r] = l_[r]*alpha[r] + rsum[r];
            #pragma unroll
            for (int d = 0; d < 4; d++)
                #pragma unroll
                for (int r = 0; r < 4; r++) O[d][r] *= alpha[r];

            #pragma unroll
            for (int nt = 0; nt < 4; nt++)
                #pragma unroll
                for (int r = 0; r < 4; r++)
                    p_lds[(w*16 + quad*4 + r)*LS + nt*16 + l16] = f2bf(P[nt][r]);
            bf16x8 pf0 = *(const bf16x8*)&p_lds[(w*16 + l16)*LS + quad*8];
            bf16x8 pf1 = *(const bf16x8*)&p_lds[(w*16 + l16)*LS + 32 + quad*8];
            #pragma unroll
            for (int d = 0; d < 4; d++) {
                bf16x8 v0f = *(const bf16x8*)&v_lds[(d*16 + l16)*LS + quad*8];
                bf16x8 v1f = *(const bf16x8*)&v_lds[(d*16 + l16)*LS + 32 + quad*8];
                O[d] = __builtin_amdgcn_mfma_f32_16x16x32_bf16(pf0, v0f, O[d], 0, 0, 0);
                O[d] = __builtin_amdgcn_mfma_f32_16x16x32_bf16(pf1, v1f, O[d], 0, 0, 0);
            }
        }

        #pragma unroll
        for (int r = 0; r < 4; r++) {
            float rl = 1.0f / l_[r];
            int tg = t0 + w*16 + quad*4 + r;
            #pragma unroll
            for (int d = 0; d < 4; d++)
                out[(size_t)(b*T_ + tg)*D_ + h*E_ + d*16 + l16] = f2bf(O[d][r] * rl);
        }
    }
}

extern "C" void kernel_launch(void* const* d_in, const int* in_sizes, int n_in,
                              void* d_out, int out_size, void* d_ws, size_t ws_size,
                              hipStream_t stream) {
    (void)in_sizes; (void)n_in; (void)out_size; (void)ws_size;
    const float* x      = (const float*)d_in[0];
    const float* wq     = (const float*)d_in[1];
    const float* wk     = (const float*)d_in[2];
    const float* wv     = (const float*)d_in[3];
    const float* w_proj = (const float*)d_in[4];
    const float* b_proj = (const float*)d_in[5];
    const float* w1     = (const float*)d_in[6];
    const float* b1     = (const float*)d_in[7];
    const float* w2     = (const float*)d_in[8];
    const float* b2     = (const float*)d_in[9];
    const float* g1     = (const float*)d_in[10];
    const float* be1    = (const float*)d_in[11];
    const float* g2     = (const float*)d_in[12];
    const float* be2    = (const float*)d_in[13];

    const size_t MB = 1024*1024;
    char* wsb = (char*)d_ws;
    u16* xn    = (u16*)(wsb + 0);          // 16MB  LN1(x) bf16
    u16* qkvb  = (u16*)(wsb + 16*MB);      // 48MB  [B*T,3072] q|k|v
    u16* h1    = (u16*)(wsb + 16*MB);      // 64MB  (reuses qkv+vT after attention)
    u16* vTb   = (u16*)(wsb + 64*MB);      // 16MB  [B*H*E, T]
    u16* attnb = (u16*)(wsb + 80*MB);      // 16MB  [B*T, D] concat heads
    u16* y1b   = (u16*)(wsb + 96*MB);      // 16MB  xn + proj out
    u16* xn2   = (u16*)(wsb + 112*MB);     // 16MB  LN2(y1)
    u16* WqkvT = (u16*)(wsb + 128*MB);     // 6MB   [3072,1024]
    u16* WprojT= (u16*)(wsb + 134*MB);     // 2MB   [1024,1024]
    u16* W1T   = (u16*)(wsb + 136*MB);     // 8MB   [4096,1024]
    u16* W2T   = (u16*)(wsb + 144*MB);     // 8MB   [1024,4096]  (ends at 152MB)
    float* P0  = (float*)(wsb + 80*MB);    // 32MB  fp32 split-K partial (attnb+y1b
                                           //       region — both dead by FFN2 time)

    // 1) LN1
    ln_f32_kernel<<<8192, 256, 0, stream>>>(x, g1, be1, xn);
    // 2) weights -> transposed bf16
    tcvt_qkv_kernel<<<dim3(1,16,48), 256, 0, stream>>>(wq, wk, wv, WqkvT);
    tcvt_kernel<<<dim3(16,16,1), 256, 0, stream>>>(w_proj, WprojT, 1024, 1024, 0, 0);
    tcvt_kernel<<<dim3(64,16,1), 256, 0, stream>>>(w1, W1T, 1024, 4096, 0, 0);
    tcvt_kernel<<<dim3(16,64,1), 256, 0, stream>>>(w2, W2T, 4096, 1024, 0, 0);
    // 3) QKV projection (fat 256x256)
    gemm_fat<<<dim3(12,32), 512, 0, stream>>>(xn, WqkvT, 8192, 3072, 1024,
                                              nullptr, nullptr, qkvb, 0);
    // 4) V -> [B,H,E,T]
    vtrans_kernel<<<dim3(16,128), 256, 0, stream>>>(qkvb, vTb);
    // 5) causal attention (paired tiles: 8 x 128 grid, 17 chunks/block)
    attn_kernel<<<dim3(8,128), 256, 0, stream>>>(qkvb, vTb, attnb);
    // 6) out projection + bias + residual(xn)  [residual uses NORMED x, faithful]
    gemm128<<<dim3(8,64,1), 256, 0, stream>>>(attnb, WprojT, 8192, 1024, 1024, 1024,
                                              b_proj, xn, y1b, nullptr, 0);
    // 7) LN2
    ln_bf16_kernel<<<8192, 256, 0, stream>>>(y1b, g2, be2, xn2);
    // 8) FFN1 + bias + relu (fat 256x256)
    gemm_fat<<<dim3(16,32), 512, 0, stream>>>(xn2, W1T, 8192, 4096, 1024,
                                              b1, nullptr, h1, 1);
    // 9) FFN2 split-K=2 via register-dieted gemm_sk (4 blocks/CU target);
    //    z=0 -> P0, z=1 -> d_out; reduce adds bias + residual(xn2)
    gemm_sk<<<dim3(8,64,2), 256, 0, stream>>>(h1, W2T, P0, (float*)d_out);
    reduce_ffn2<<<8192, 256, 0, stream>>>(P0, (float*)d_out, b2, xn2);
}